// Round 13
// baseline (220.307 us; speedup 1.0000x reference)
//
#include <hip/hip_runtime.h>
#include <math.h>

typedef __attribute__((ext_vector_type(8))) short short8;
typedef __attribute__((ext_vector_type(4))) float f32x4;
typedef __attribute__((ext_vector_type(2))) unsigned int u32x2;

#define AS1 __attribute__((address_space(1)))
#define AS3 __attribute__((address_space(3)))

__device__ __forceinline__ float b2f(short s){
  return __uint_as_float(((unsigned int)(unsigned short)s) << 16);
}
__device__ __forceinline__ short f2b(float f){
  unsigned int u = __float_as_uint(f);
  u = (u + 0x7fffu + ((u >> 16) & 1u)) >> 16;
  return (short)u;
}
__device__ __forceinline__ unsigned pk2(float lo, float hi){
  return ((unsigned)(unsigned short)f2b(hi) << 16) | (unsigned)(unsigned short)f2b(lo);
}

// -------- weight f32 -> bf16, permuted to BFRAG order [s][nt][lane][8] -------
// element (mat, N=row, K=col): s=col>>5, g=(col>>3)&3, j=col&7, nt=row>>4,
// l15=row&15, lane=g*16+l15  ->  d = mat*65536 + (s*16+nt)*512 + lane*8 + j.
// GEMM B-fragment (s,nt) load = base + lane*16B : fully coalesced from L2.
__global__ __launch_bounds__(256) void cvt_w(
    const float* __restrict__ s0, const float* __restrict__ s1,
    const float* __restrict__ s2, const float* __restrict__ s3,
    const float* __restrict__ s4, const float* __restrict__ s5,
    short* __restrict__ dst)
{
  const float* srcs[6] = {s0, s1, s2, s3, s4, s5};
  int i = blockIdx.x * 256 + threadIdx.x;       // 6*65536 total
  int mat = i >> 16, rc = i & 65535;
  int row = rc >> 8, col = rc & 255;
  int s = col >> 5, g2 = (col >> 3) & 3, j = col & 7;
  int nt = row >> 4, l15 = row & 15;
  int d = mat * 65536 + (((s << 4) + nt) << 9) + (((g2 << 4) + l15) << 3) + j;
  dst[d] = f2b(srcs[mat][rc]);
}

// ---------------- LayerNorm f32 -> bf16 afrag writer -------------------------
// Block = 1 tile (64 rows), 256 thr (4 thr/row, 64 cols each).
// afrag: chunk (tile,s,w,lane=g*16+l15) = row w*16+l15, cols s*32+g*8 (16B).
__global__ __launch_bounds__(256) void lnq_k(
    const float* __restrict__ x, const float* __restrict__ g,
    const float* __restrict__ bta, short* __restrict__ af)
{
  const int tile = blockIdx.x, tid = threadIdx.x;
  const int row = tid >> 2, c0 = (tid & 3) << 6;
  const float* src = &x[((size_t)tile * 64 + row) * 256 + c0];
  float vv[64];
  #pragma unroll
  for (int i = 0; i < 16; ++i) *(f32x4*)&vv[4 * i] = *(const f32x4*)&src[4 * i];
  float s1 = 0.f, s2 = 0.f;
  #pragma unroll
  for (int i = 0; i < 64; ++i){ s1 += vv[i]; s2 += vv[i] * vv[i]; }
  s1 += __shfl_xor(s1, 1); s2 += __shfl_xor(s2, 1);
  s1 += __shfl_xor(s1, 2); s2 += __shfl_xor(s2, 2);
  const float mu = s1 * 0.00390625f;
  const float rs = rsqrtf(s2 * 0.00390625f - mu * mu + 1e-5f);
  const int w = row >> 4, l15 = row & 15;
  #pragma unroll
  for (int i = 0; i < 8; ++i){
    const int col0 = c0 + 8 * i;
    f32x4 g0 = *(const f32x4*)&g[col0],   g1 = *(const f32x4*)&g[col0 + 4];
    f32x4 b0 = *(const f32x4*)&bta[col0], b1 = *(const f32x4*)&bta[col0 + 4];
    short8 o;
    #pragma unroll
    for (int j = 0; j < 4; ++j) o[j] = f2b((vv[8 * i + j] - mu) * rs * g0[j] + b0[j]);
    #pragma unroll
    for (int j = 0; j < 4; ++j) o[4 + j] = f2b((vv[8 * i + 4 + j] - mu) * rs * g1[j] + b1[j]);
    const int s = col0 >> 5, gg = (col0 >> 3) & 3;
    *(short8*)&af[((((size_t)tile * 8 + s) * 4 + w) * 64 + gg * 16 + l15) * 8] = o;
  }
}

// -------- barrier-free LDS-free GEMM: C[M,256] = A @ W^T + b -----------------
// Block = 1 tile (64 rows x 256 cols), 4 waves. A in afrag regs (8 coalesced
// 1KB loads), W read directly from L2 in bfrag order (coalesced 1KB/load).
// NO LDS, NO barriers. Epilogue: GELU / RES f32 residual / OF f32 out /
// OT: 1 kfrag, 2 vfrag, 4 afrag / LNO: row-LN -> afrag outL.
template<int GELU, int RES, int OF, int OT, int LNO>
__global__ __launch_bounds__(256, 3) void gemmB(
    const short* __restrict__ Aaf, const short* __restrict__ Wb,
    const float* __restrict__ bias, const float* __restrict__ resF,
    float* __restrict__ outF, short* __restrict__ outT,
    const float* __restrict__ lng, const float* __restrict__ lnb,
    short* __restrict__ outL)
{
  const int tid = threadIdx.x;
  const int tile = blockIdx.x;
  const int w = tid >> 6, lane = tid & 63;
  const int l15 = lane & 15, g = lane >> 4;

  // ---- A fragments (coalesced 1KB per wave-instr) ----
  short8 afr[8];
  #pragma unroll
  for (int s = 0; s < 8; ++s)
    afr[s] = *(const short8*)&Aaf[((((size_t)tile << 3) + s) * 4 + w) * 512 + (lane << 3)];

  f32x4 acc[16];
  #pragma unroll
  for (int nt = 0; nt < 16; ++nt) acc[nt] = {0.f, 0.f, 0.f, 0.f};

  #pragma unroll
  for (int s = 0; s < 8; ++s){
    const short8 af = afr[s];
    #pragma unroll
    for (int nt = 0; nt < 16; ++nt){
      short8 bf = *(const short8*)&Wb[(((s << 4) + nt) << 9) + (lane << 3)];
      acc[nt] = __builtin_amdgcn_mfma_f32_16x16x32_bf16(af, bf, acc[nt], 0, 0, 0);
    }
  }

  // ---- epilogue ----
  const int m0 = tile << 6;
  const int row_l = (w << 4) + (g << 2);
  #pragma unroll
  for (int nt = 0; nt < 16; ++nt){
    const int col = (nt << 4) + l15;
    const float bv = bias[col];
    #pragma unroll
    for (int r = 0; r < 4; ++r){
      const int m = m0 + row_l + r;
      const size_t idx = (size_t)m * 256 + col;
      float v = acc[nt][r] + bv;
      if (GELU) v = 0.5f * v * (1.0f + erff(v * 0.70710678118f));
      if (RES) v += resF[idx];
      if (OF) outF[idx] = v;
      acc[nt][r] = v;
      if (OT == 1){   // kfrag: [b][h][nt16][half][g][l15][8]
        const int b_ = m >> 8, kvr = m & 255;
        const int knt = kvr >> 4, kl = kvr & 15;
        const int h = col >> 6, half = (col >> 5) & 1, kg = (col >> 3) & 3, kj = col & 7;
        outT[(((((size_t)(b_ * 4 + h) * 16 + knt) * 2 + half) * 4 + kg) * 16 + kl) * 8 + kj] = f2b(v);
      }
      if (OT == 2){   // vfrag: [b][h][kk][n2][g][l15][8]
        const int b_ = m >> 8, kvj = m & 255;
        const int jp = (kvj & ~31) | (((kvj >> 2) & 3) << 3) | (((kvj >> 4) & 1) << 2) | (kvj & 3);
        const int h = col >> 6, dp = col & 63;
        const int kk = jp >> 5, vg = (jp >> 3) & 3, vj = jp & 7;
        const int vn2 = dp >> 4, vl = dp & 15;
        outT[(((((size_t)(b_ * 4 + h) * 8 + kk) * 4 + vn2) * 4 + vg) * 16 + vl) * 8 + vj] = f2b(v);
      }
      if (OT == 4){   // standard afrag
        outT[((((size_t)tile * 8 + (col >> 5)) * 4 + w) * 64
              + (((col >> 3) & 3) << 4) + (g << 2) + r) * 8 + (col & 7)] = f2b(v);
      }
    }
  }
  if (LNO){
    #pragma unroll
    for (int r = 0; r < 4; ++r){
      float s1 = 0.f, s2 = 0.f;
      #pragma unroll
      for (int nt = 0; nt < 16; ++nt){ float v = acc[nt][r]; s1 += v; s2 += v * v; }
      #pragma unroll
      for (int off = 1; off < 16; off <<= 1){ s1 += __shfl_xor(s1, off); s2 += __shfl_xor(s2, off); }
      const float mu = s1 * 0.00390625f;
      const float rs = rsqrtf(s2 * 0.00390625f - mu * mu + 1e-5f);
      #pragma unroll
      for (int nt = 0; nt < 16; ++nt){
        const int col = (nt << 4) + l15;
        float lv = (acc[nt][r] - mu) * rs * lng[col] + lnb[col];
        outL[((((size_t)tile * 8 + (col >> 5)) * 4 + w) * 64
              + (((col >> 3) & 3) << 4) + (g << 2) + r) * 8 + (col & 7)] = f2b(lv);
      }
    }
  }
}

// ---------------- fused MFMA attention: 32KB LDS, V direct from L2 -----------
// Block: 256 thr = 4 waves x 16 q-rows; grid 64x8 = 512 blocks.
// LDS 32KB = single K buffer (stage K(h+1) after QK barrier, overlapping
// softmax+PV). V B-frags read directly from L2 (coalesced vfrag).
// cw: 1KB bursts -> swizzled LDS bounce -> packed regs. Q from afrag.
// ctx written in afrag order. am via 2-round LDS bounce -> 1KB-burst stores.
__global__ __launch_bounds__(256, 2) void attn_k(
    const short* __restrict__ Qf, const short* __restrict__ Kf,
    const short* __restrict__ Vf, const float* __restrict__ cw,
    short* __restrict__ ctx, float* __restrict__ am_out)
{
  extern __shared__ __align__(16) short smem[];   // 16384 shorts = 32KB
  short* Kl = smem;
  const int b = blockIdx.y;
  const int q0 = blockIdx.x << 6;
  const int tid = threadIdx.x;
  const int w = tid >> 6, lane = tid & 63;
  const int l15 = lane & 15, g = lane >> 4;
  const size_t qw = (size_t)b * 4096 + q0 + (w << 4);   // wave's first q row
  const size_t qblk = qw >> 4;
  const size_t tileQ = qblk >> 2;
  const int wQ = (int)(qblk & 3);
  const size_t tileC = (size_t)b * 64 + blockIdx.x;     // ctx afrag tile

#define STG(dst_, src_) do{ _Pragma("unroll")                                        \
  for (int it_ = 0; it_ < 8; ++it_){ int c_ = (it_ << 8) + tid;                      \
    __builtin_amdgcn_global_load_lds((const AS1 void*)((src_) + (c_ << 3)),          \
                                     (AS3 void*)((dst_) + (c_ << 3)), 16, 0, 0); } }while(0)

  // ---- cw: full-row coalesced load -> swizzled LDS -> scattered reg read ----
  unsigned cwp[16][2];
  f32x4 am[16];
  {
    char* reg = (char*)smem + (w << 13);       // 8KB per wave (fits 32KB)
    #pragma unroll
    for (int j = 0; j < 16; ++j){
      f32x4 v = *(const f32x4*)&cw[(qw + j) * 256 + (lane << 2)];  // 1KB burst/instr
      u32x2 d = { pk2(v[0], v[1]), pk2(v[2], v[3]) };
      unsigned off = ((j << 9) + (lane << 3)) ^ ((j & 7) << 4);
      *(u32x2*)(reg + off) = d;
    }
    __syncthreads();
    #pragma unroll
    for (int nt = 0; nt < 16; ++nt){
      unsigned base = ((l15 << 9) + (nt << 5) + (g << 3)) ^ ((l15 & 7) << 4);
      cwp[nt][0] = *(const unsigned*)(reg + base);
      cwp[nt][1] = *(const unsigned*)(reg + base + 4);
      am[nt] = {0.f, 0.f, 0.f, 0.f};
    }
    __syncthreads();
  }

  STG(Kl, Kf + ((size_t)(b * 4) << 14));
  __syncthreads();                       // K(0) staged

  for (int h = 0; h < 4; ++h){
    const short* vh = Vf + ((size_t)(b * 4 + h) << 14);
    short8 qf0 = *(const short8*)&Qf[(((tileQ * 8 + (h << 1)) * 4 + wQ) * 64 + lane) * 8];
    short8 qf1 = *(const short8*)&Qf[(((tileQ * 8 + (h << 1) + 1) * 4 + wQ) * 64 + lane) * 8];

    // ---- scores: swapped operands, lane-contiguous ds_read_b128 ----
    f32x4 acc[16];
    #pragma unroll
    for (int nt = 0; nt < 16; ++nt) acc[nt] = {0.f, 0.f, 0.f, 0.f};
    #pragma unroll
    for (int nt = 0; nt < 16; ++nt){
      short8 kf0 = *(const short8*)&Kl[(nt << 10) + (lane << 3)];
      acc[nt] = __builtin_amdgcn_mfma_f32_16x16x32_bf16(kf0, qf0, acc[nt], 0, 0, 0);
      short8 kf1 = *(const short8*)&Kl[(nt << 10) + 512 + (lane << 3)];
      acc[nt] = __builtin_amdgcn_mfma_f32_16x16x32_bf16(kf1, qf1, acc[nt], 0, 0, 0);
    }
    __syncthreads();                     // all waves done reading Kl
    if (h < 3) STG(Kl, Kf + ((size_t)(b * 4 + h + 1) << 14));   // overlaps SM+PV

    // ---- softmax, fully in-lane (row q = l15; partners at lane^16, lane^32) ----
    float mx = -3.4e38f;
    #pragma unroll
    for (int nt = 0; nt < 16; ++nt){
      float c0 = __uint_as_float(cwp[nt][0] << 16);
      float c1 = __uint_as_float(cwp[nt][0] & 0xffff0000u);
      float c2 = __uint_as_float(cwp[nt][1] << 16);
      float c3 = __uint_as_float(cwp[nt][1] & 0xffff0000u);
      acc[nt][0] = acc[nt][0] * 0.125f + c0;
      acc[nt][1] = acc[nt][1] * 0.125f + c1;
      acc[nt][2] = acc[nt][2] * 0.125f + c2;
      acc[nt][3] = acc[nt][3] * 0.125f + c3;
      mx = fmaxf(mx, fmaxf(fmaxf(acc[nt][0], acc[nt][1]), fmaxf(acc[nt][2], acc[nt][3])));
    }
    mx = fmaxf(mx, __shfl_xor(mx, 16));
    mx = fmaxf(mx, __shfl_xor(mx, 32));
    float sm = 0.f;
    #pragma unroll
    for (int nt = 0; nt < 16; ++nt){
      #pragma unroll
      for (int r = 0; r < 4; ++r){
        float e = __expf(acc[nt][r] - mx);
        acc[nt][r] = e; sm += e;
      }
    }
    sm += __shfl_xor(sm, 16);
    sm += __shfl_xor(sm, 32);
    float inv = 1.f / sm;
    #pragma unroll
    for (int nt = 0; nt < 16; ++nt){
      #pragma unroll
      for (int r = 0; r < 4; ++r){
        float p = acc[nt][r] * inv;
        acc[nt][r] = p;
        am[nt][r] += 0.25f * p;
      }
    }
    // ---- ctx = P @ V : in-lane A packs; V frags direct from L2 (coalesced) --
    f32x4 oc[4] = {{0,0,0,0},{0,0,0,0},{0,0,0,0},{0,0,0,0}};
    #pragma unroll
    for (int kk = 0; kk < 8; ++kk){
      union { short8 s; unsigned u[4]; } pa;
      pa.u[0] = pk2(acc[2 * kk][0],     acc[2 * kk][1]);
      pa.u[1] = pk2(acc[2 * kk][2],     acc[2 * kk][3]);
      pa.u[2] = pk2(acc[2 * kk + 1][0], acc[2 * kk + 1][1]);
      pa.u[3] = pk2(acc[2 * kk + 1][2], acc[2 * kk + 1][3]);
      #pragma unroll
      for (int n2 = 0; n2 < 4; ++n2){
        short8 vb = *(const short8*)&vh[(((kk << 2) + n2) << 9) + (lane << 3)];
        oc[n2] = __builtin_amdgcn_mfma_f32_16x16x32_bf16(pa.s, vb, oc[n2], 0, 0, 0);
      }
    }
    // ctx -> standard afrag (for O-GEMM): row m = qw+g*4+r, col = h*64+n2*16+l15
    #pragma unroll
    for (int n2 = 0; n2 < 4; ++n2){
      const int sctx = (h << 1) + (n2 >> 1);
      const int gctx = ((n2 & 1) << 1) + (l15 >> 3);
      const int j = l15 & 7;
      #pragma unroll
      for (int r = 0; r < 4; ++r)
        ctx[(((tileC * 8 + sctx) * 4 + w) * 64 + (gctx << 4) + (g << 2) + r) * 8 + j]
            = f2b(oc[n2][r]);
    }
    __syncthreads();                     // K(h+1) staged; Kl safe to read
  }

  // ---- am: 2-round scatter into swizzled 32KB LDS, 1KB-burst stores --------
  #pragma unroll
  for (int round = 0; round < 2; ++round){
    __syncthreads();
    if ((w >> 1) == round){
      char* reg = (char*)smem + ((w & 1) << 14);   // 16KB per wave
      #pragma unroll
      for (int nt = 0; nt < 16; ++nt){
        unsigned off = ((l15 << 10) + (nt << 6) + (g << 4)) ^ ((l15 & 7) << 4);
        *(f32x4*)(reg + off) = am[nt];
      }
    }
    __syncthreads();
    #pragma unroll
    for (int i2 = 0; i2 < 8; ++i2){
      unsigned fb = (tid << 4) + (i2 << 12);       // flat byte 0..32767
      unsigned rowin = (fb >> 10) & 15;
      f32x4 v = *(const f32x4*)((char*)smem + (fb ^ ((rowin & 7) << 4)));
      unsigned row = (round << 5) + (fb >> 10);    // 0..63 within block
      *(f32x4*)&am_out[((size_t)b * 4096 + q0 + row) * 256 + ((fb & 1023) >> 2)] = v;
    }
  }
#undef STG
}

extern "C" void kernel_launch(void* const* d_in, const int* in_sizes, int n_in,
                              void* d_out, int out_size, void* d_ws, size_t ws_size,
                              hipStream_t stream)
{
  const float* node_emb = (const float*)d_in[0];
  const float* cluster  = (const float*)d_in[1];
  const float* cw       = (const float*)d_in[2];
  const float* ln_q_g   = (const float*)d_in[3];
  const float* ln_q_b   = (const float*)d_in[4];
  const float* ln_kv_g  = (const float*)d_in[5];
  const float* ln_kv_b  = (const float*)d_in[6];
  const float* ln_o_g   = (const float*)d_in[7];
  const float* ln_o_b   = (const float*)d_in[8];
  const float* W_q  = (const float*)d_in[9];  const float* b_q  = (const float*)d_in[10];
  const float* W_k  = (const float*)d_in[11]; const float* b_k  = (const float*)d_in[12];
  const float* W_v  = (const float*)d_in[13]; const float* b_v  = (const float*)d_in[14];
  const float* W_o  = (const float*)d_in[15]; const float* b_o  = (const float*)d_in[16];
  const float* W_m1 = (const float*)d_in[17]; const float* b_m1 = (const float*)d_in[18];
  const float* W_m2 = (const float*)d_in[19]; const float* b_m2 = (const float*)d_in[20];

  char* ws = (char*)d_ws;
  short* Wbf   = (short*)ws;                                   // 786,432 B (bfrag order)
  short* bufA  = (short*)(ws + 786432);                        // 16.78 MB: afnode -> ctx -> h1
  short* bufB  = (short*)(ws + 786432 + 16777216);             // 16.78 MB: Qaf -> lnx
  short* kvaf  = (short*)(ws + 786432 + 2 * 16777216);         // 1 MB
  short* kfrag = (short*)(ws + 786432 + 2 * 16777216 + 1048576);
  short* vfrag = (short*)(ws + 786432 + 2 * 16777216 + 2 * 1048576);

  float* xbuf = (float*)d_out;            // first half: x, then final out (in-place)
  float* amof = (float*)d_out + 8388608;  // second half: attn_matrix

  hipFuncSetAttribute((const void*)attn_k, hipFuncAttributeMaxDynamicSharedMemorySize, 32768);

  cvt_w<<<1536, 256, 0, stream>>>(W_q, W_k, W_v, W_o, W_m1, W_m2, Wbf);
  // input LayerNorms -> afrag
  lnq_k<<<512, 256, 0, stream>>>(node_emb, ln_q_g, ln_q_b, bufA);
  lnq_k<<<32, 256, 0, stream>>>(cluster, ln_kv_g, ln_kv_b, kvaf);
  // Q projection -> afrag (bufB)
  gemmB<0,0,0,4,0><<<512, 256, 0, stream>>>(bufA, Wbf, b_q,
      nullptr, nullptr, bufB, nullptr, nullptr, nullptr);
  // K / V projections -> kfrag / vfrag
  gemmB<0,0,0,1,0><<<32, 256, 0, stream>>>(kvaf, Wbf + 65536, b_k,
      nullptr, nullptr, kfrag, nullptr, nullptr, nullptr);
  gemmB<0,0,0,2,0><<<32, 256, 0, stream>>>(kvaf, Wbf + 131072, b_v,
      nullptr, nullptr, vfrag, nullptr, nullptr, nullptr);
  // attention (ctx afrag -> bufA, attn_matrix -> d_out 2nd half)
  attn_k<<<dim3(64, 8), 256, 32768, stream>>>(bufB, kfrag, vfrag, cw, bufA, amof);
  // O proj + residual(node_emb) -> x f32 (d_out) + LN(x) afrag (bufB)
  gemmB<0,1,1,0,1><<<512, 256, 0, stream>>>(bufA, Wbf + 196608, b_o,
      node_emb, xbuf, nullptr, ln_o_g, ln_o_b, bufB);
  // MLP1 + GELU -> h1 afrag (bufA)
  gemmB<1,0,0,4,0><<<512, 256, 0, stream>>>(bufB, Wbf + 262144, b_m1,
      nullptr, nullptr, bufA, nullptr, nullptr, nullptr);
  // MLP2 + residual(x) -> final out f32 (in-place over x, same-index)
  gemmB<0,1,1,0,0><<<512, 256, 0, stream>>>(bufA, Wbf + 327680, b_m2,
      xbuf, xbuf, nullptr, nullptr, nullptr, nullptr);
}

// Round 15
// 129.048 us; speedup vs baseline: 1.7072x; 1.7072x over previous
//
#include <hip/hip_runtime.h>
#include <math.h>

typedef __attribute__((ext_vector_type(8))) short short8;
typedef __attribute__((ext_vector_type(4))) float f32x4;
typedef __attribute__((ext_vector_type(2))) unsigned int u32x2;

#define AS1 __attribute__((address_space(1)))
#define AS3 __attribute__((address_space(3)))

__device__ __forceinline__ float b2f(short s){
  return __uint_as_float(((unsigned int)(unsigned short)s) << 16);
}
__device__ __forceinline__ short f2b(float f){
  unsigned int u = __float_as_uint(f);
  u = (u + 0x7fffu + ((u >> 16) & 1u)) >> 16;
  return (short)u;
}
__device__ __forceinline__ unsigned pk2(float lo, float hi){
  return ((unsigned)(unsigned short)f2b(hi) << 16) | (unsigned)(unsigned short)f2b(lo);
}

// ---------------- weight f32 -> bf16 (row-major, r8-proven) ----------------
__global__ __launch_bounds__(256) void cvt_w(
    const float* __restrict__ s0, const float* __restrict__ s1,
    const float* __restrict__ s2, const float* __restrict__ s3,
    const float* __restrict__ s4, const float* __restrict__ s5,
    short* __restrict__ dst)
{
  const float* srcs[6] = {s0, s1, s2, s3, s4, s5};
  int i = blockIdx.x * 256 + threadIdx.x;       // 6*65536 total
  dst[i] = f2b(srcs[i >> 16][i & 65535]);
}

// ---------------- LayerNorm: f32 in, bf16 out (kv path) ----------------
__global__ __launch_bounds__(256) void ln_k(
    const float* __restrict__ x, const float* __restrict__ g,
    const float* __restrict__ bta, short* __restrict__ y)
{
  const int row = blockIdx.x, t = threadIdx.x;
  const size_t base = (size_t)row * 256;
  float v = x[base + t];
  float s1 = v, s2 = v * v;
  #pragma unroll
  for (int off = 32; off; off >>= 1){ s1 += __shfl_down(s1, off); s2 += __shfl_down(s2, off); }
  __shared__ float a1[4], a2[4];
  __shared__ float mu_s, rs_s;
  if ((t & 63) == 0){ a1[t >> 6] = s1; a2[t >> 6] = s2; }
  __syncthreads();
  if (t == 0){
    float S1 = a1[0] + a1[1] + a1[2] + a1[3];
    float S2 = a2[0] + a2[1] + a2[2] + a2[3];
    float mu = S1 * 0.00390625f;
    float var = S2 * 0.00390625f - mu * mu;
    mu_s = mu; rs_s = rsqrtf(var + 1e-5f);
  }
  __syncthreads();
  y[base + t] = f2b((v - mu_s) * rs_s * g[t] + bta[t]);
}

// ---------------- wide GEMM (r8-proven body): C = A @ W^T + b ----------------
// Block = 64 rows x 256 cols, 4 waves. A staged once to padded LDS (LNA=1:
// f32 + fused LN). W double-buffered per 32-k-step via register round-trip.
// Epilogue: OT: 1 kfrag, 2 vfrag, 4 standard afrag.
template<int OT, int LNA>
__global__ __launch_bounds__(256, 2) void gemmW(
    const short* __restrict__ A, const float* __restrict__ Af,
    const short* __restrict__ W, const float* __restrict__ bias,
    short* __restrict__ outB,
    const float* __restrict__ lnag, const float* __restrict__ lnab)
{
  __shared__ short As[64][264];
  __shared__ short Ws[2][256][40];
  const int tid = threadIdx.x;
  const int m0 = blockIdx.x << 6;
  const int w = tid >> 6, lane = tid & 63;
  const int l15 = lane & 15, g = lane >> 4;

  if (LNA){
    const int row = tid >> 2, c0 = (tid & 3) << 6;
    float vv[64];
    const float* src = &Af[(size_t)(m0 + row) * 256 + c0];
    #pragma unroll
    for (int i = 0; i < 16; ++i) *(f32x4*)&vv[4 * i] = *(const f32x4*)&src[4 * i];
    float s1 = 0.f, s2 = 0.f;
    #pragma unroll
    for (int i = 0; i < 64; ++i){ s1 += vv[i]; s2 += vv[i] * vv[i]; }
    s1 += __shfl_xor(s1, 1); s2 += __shfl_xor(s2, 1);
    s1 += __shfl_xor(s1, 2); s2 += __shfl_xor(s2, 2);
    const float mu = s1 * 0.00390625f;
    const float rs = rsqrtf(s2 * 0.00390625f - mu * mu + 1e-5f);
    #pragma unroll
    for (int i = 0; i < 8; ++i){
      f32x4 gv0 = *(const f32x4*)&lnag[c0 + 8 * i];
      f32x4 gv1 = *(const f32x4*)&lnag[c0 + 8 * i + 4];
      f32x4 bv0 = *(const f32x4*)&lnab[c0 + 8 * i];
      f32x4 bv1 = *(const f32x4*)&lnab[c0 + 8 * i + 4];
      short8 o;
      #pragma unroll
      for (int j = 0; j < 4; ++j) o[j] = f2b((vv[8 * i + j] - mu) * rs * gv0[j] + bv0[j]);
      #pragma unroll
      for (int j = 0; j < 4; ++j) o[4 + j] = f2b((vv[8 * i + 4 + j] - mu) * rs * gv1[j] + bv1[j]);
      *(short8*)&As[row][c0 + 8 * i] = o;
    }
  } else {
    #pragma unroll
    for (int it = 0; it < 8; ++it){
      int idx = tid + (it << 8);
      int row = idx >> 5, c = (idx & 31) << 3;
      *(short8*)&As[row][c] = *(const short8*)&A[(size_t)(m0 + row) * 256 + c];
    }
  }
  #pragma unroll
  for (int it = 0; it < 4; ++it){
    int row = (it << 6) + (tid >> 2), c = (tid & 3) << 3;
    *(short8*)&Ws[0][row][c] = *(const short8*)&W[(size_t)row * 256 + c];
  }
  __syncthreads();

  f32x4 acc[16];
  #pragma unroll
  for (int nt = 0; nt < 16; ++nt) acc[nt] = {0.f, 0.f, 0.f, 0.f};

  int cur = 0;
  for (int s = 0; s < 8; ++s){
    const int k0 = s << 5;
    short8 wreg[4];
    if (s < 7){
      #pragma unroll
      for (int it = 0; it < 4; ++it)
        wreg[it] = *(const short8*)&W[(size_t)((it << 6) + (tid >> 2)) * 256 + k0 + 32 + ((tid & 3) << 3)];
    }
    short8 af = *(const short8*)&As[(w << 4) + l15][k0 + (g << 3)];
    #pragma unroll
    for (int nt = 0; nt < 16; ++nt){
      short8 bf = *(const short8*)&Ws[cur][(nt << 4) + l15][g << 3];
      acc[nt] = __builtin_amdgcn_mfma_f32_16x16x32_bf16(af, bf, acc[nt], 0, 0, 0);
    }
    if (s < 7){
      #pragma unroll
      for (int it = 0; it < 4; ++it)
        *(short8*)&Ws[cur ^ 1][(it << 6) + (tid >> 2)][(tid & 3) << 3] = wreg[it];
    }
    __syncthreads();
    cur ^= 1;
  }

  const int row_l = (w << 4) + (g << 2);
  #pragma unroll
  for (int nt = 0; nt < 16; ++nt){
    const int col = (nt << 4) + l15;
    const float bv = bias[col];
    #pragma unroll
    for (int r = 0; r < 4; ++r){
      const int m = m0 + row_l + r;
      float v = acc[nt][r] + bv;
      if (OT == 1){   // kfrag: [b][h][nt16][half][g][l15][8]
        const int b_ = m >> 8, kvr = m & 255;
        const int knt = kvr >> 4, kl = kvr & 15;
        const int h = col >> 6, half = (col >> 5) & 1, kg = (col >> 3) & 3, kj = col & 7;
        outB[(((((size_t)(b_ * 4 + h) * 16 + knt) * 2 + half) * 4 + kg) * 16 + kl) * 8 + kj] = f2b(v);
      }
      if (OT == 2){   // vfrag: [b][h][kk][n2][g][l15][8]
        const int b_ = m >> 8, kvj = m & 255;
        const int jp = (kvj & ~31) | (((kvj >> 2) & 3) << 3) | (((kvj >> 4) & 1) << 2) | (kvj & 3);
        const int h = col >> 6, dp = col & 63;
        const int kk = jp >> 5, vg = (jp >> 3) & 3, vj = jp & 7;
        const int vn2 = dp >> 4, vl = dp & 15;
        outB[(((((size_t)(b_ * 4 + h) * 8 + kk) * 4 + vn2) * 4 + vg) * 16 + vl) * 8 + vj] = f2b(v);
      }
      if (OT == 4){   // standard afrag
        outB[((((size_t)blockIdx.x * 8 + (col >> 5)) * 4 + w) * 64
              + (((col >> 3) & 3) << 4) + (g << 2) + r) * 8 + (col & 7)] = f2b(v);
      }
    }
  }
}

// ---------------- fused MFMA attention (r12-proven, verbatim) ----------------
__global__ __launch_bounds__(256, 2) void attn_k(
    const short* __restrict__ Qf, const short* __restrict__ Kf,
    const short* __restrict__ Vf, const float* __restrict__ cw,
    short* __restrict__ ctx, float* __restrict__ am_out)
{
  extern __shared__ __align__(16) short smem[];   // 32768 shorts = 64KB
  short* Kl = smem;
  short* Vl = smem + 16384;
  const int b = blockIdx.y;
  const int q0 = blockIdx.x << 6;
  const int tid = threadIdx.x;
  const int w = tid >> 6, lane = tid & 63;
  const int l15 = lane & 15, g = lane >> 4;
  const size_t qw = (size_t)b * 4096 + q0 + (w << 4);
  const size_t qblk = qw >> 4;
  const size_t tileQ = qblk >> 2;
  const int wQ = (int)(qblk & 3);
  const size_t tileC = (size_t)b * 64 + blockIdx.x;

#define STG(dst_, src_) do{ _Pragma("unroll")                                        \
  for (int it_ = 0; it_ < 8; ++it_){ int c_ = (it_ << 8) + tid;                      \
    __builtin_amdgcn_global_load_lds((const AS1 void*)((src_) + (c_ << 3)),          \
                                     (AS3 void*)((dst_) + (c_ << 3)), 16, 0, 0); } }while(0)

  unsigned cwp[16][2];
  f32x4 am[16];
  {
    char* reg = (char*)smem + (w << 13);
    #pragma unroll
    for (int j = 0; j < 16; ++j){
      f32x4 v = *(const f32x4*)&cw[(qw + j) * 256 + (lane << 2)];
      u32x2 d = { pk2(v[0], v[1]), pk2(v[2], v[3]) };
      unsigned off = ((j << 9) + (lane << 3)) ^ ((j & 7) << 4);
      *(u32x2*)(reg + off) = d;
    }
    __syncthreads();
    #pragma unroll
    for (int nt = 0; nt < 16; ++nt){
      unsigned base = ((l15 << 9) + (nt << 5) + (g << 3)) ^ ((l15 & 7) << 4);
      cwp[nt][0] = *(const unsigned*)(reg + base);
      cwp[nt][1] = *(const unsigned*)(reg + base + 4);
      am[nt] = {0.f, 0.f, 0.f, 0.f};
    }
    __syncthreads();
  }

  STG(Kl, Kf + ((size_t)(b * 4) << 14));
  __syncthreads();

  for (int h = 0; h < 4; ++h){
    STG(Vl, Vf + ((size_t)(b * 4 + h) << 14));
    short8 qf0 = *(const short8*)&Qf[(((tileQ * 8 + (h << 1)) * 4 + wQ) * 64 + lane) * 8];
    short8 qf1 = *(const short8*)&Qf[(((tileQ * 8 + (h << 1) + 1) * 4 + wQ) * 64 + lane) * 8];

    f32x4 acc[16];
    #pragma unroll
    for (int nt = 0; nt < 16; ++nt) acc[nt] = {0.f, 0.f, 0.f, 0.f};
    #pragma unroll
    for (int nt = 0; nt < 16; ++nt){
      short8 kf0 = *(const short8*)&Kl[(nt << 10) + (lane << 3)];
      acc[nt] = __builtin_amdgcn_mfma_f32_16x16x32_bf16(kf0, qf0, acc[nt], 0, 0, 0);
      short8 kf1 = *(const short8*)&Kl[(nt << 10) + 512 + (lane << 3)];
      acc[nt] = __builtin_amdgcn_mfma_f32_16x16x32_bf16(kf1, qf1, acc[nt], 0, 0, 0);
    }
    __syncthreads();
    if (h < 3) STG(Kl, Kf + ((size_t)(b * 4 + h + 1) << 14));

    float mx = -3.4e38f;
    #pragma unroll
    for (int nt = 0; nt < 16; ++nt){
      float c0 = __uint_as_float(cwp[nt][0] << 16);
      float c1 = __uint_as_float(cwp[nt][0] & 0xffff0000u);
      float c2 = __uint_as_float(cwp[nt][1] << 16);
      float c3 = __uint_as_float(cwp[nt][1] & 0xffff0000u);
      acc[nt][0] = acc[nt][0] * 0.125f + c0;
      acc[nt][1] = acc[nt][1] * 0.125f + c1;
      acc[nt][2] = acc[nt][2] * 0.125f + c2;
      acc[nt][3] = acc[nt][3] * 0.125f + c3;
      mx = fmaxf(mx, fmaxf(fmaxf(acc[nt][0], acc[nt][1]), fmaxf(acc[nt][2], acc[nt][3])));
    }
    mx = fmaxf(mx, __shfl_xor(mx, 16));
    mx = fmaxf(mx, __shfl_xor(mx, 32));
    float sm = 0.f;
    #pragma unroll
    for (int nt = 0; nt < 16; ++nt){
      #pragma unroll
      for (int r = 0; r < 4; ++r){
        float e = __expf(acc[nt][r] - mx);
        acc[nt][r] = e; sm += e;
      }
    }
    sm += __shfl_xor(sm, 16);
    sm += __shfl_xor(sm, 32);
    float inv = 1.f / sm;
    #pragma unroll
    for (int nt = 0; nt < 16; ++nt){
      #pragma unroll
      for (int r = 0; r < 4; ++r){
        float p = acc[nt][r] * inv;
        acc[nt][r] = p;
        am[nt][r] += 0.25f * p;
      }
    }
    f32x4 oc[4] = {{0,0,0,0},{0,0,0,0},{0,0,0,0},{0,0,0,0}};
    #pragma unroll
    for (int kk = 0; kk < 8; ++kk){
      union { short8 s; unsigned u[4]; } pa;
      pa.u[0] = pk2(acc[2 * kk][0],     acc[2 * kk][1]);
      pa.u[1] = pk2(acc[2 * kk][2],     acc[2 * kk][3]);
      pa.u[2] = pk2(acc[2 * kk + 1][0], acc[2 * kk + 1][1]);
      pa.u[3] = pk2(acc[2 * kk + 1][2], acc[2 * kk + 1][3]);
      #pragma unroll
      for (int n2 = 0; n2 < 4; ++n2){
        short8 vb = *(const short8*)&Vl[(((kk << 2) + n2) << 9) + (lane << 3)];
        oc[n2] = __builtin_amdgcn_mfma_f32_16x16x32_bf16(pa.s, vb, oc[n2], 0, 0, 0);
      }
    }
    #pragma unroll
    for (int n2 = 0; n2 < 4; ++n2){
      const int sctx = (h << 1) + (n2 >> 1);
      const int gctx = ((n2 & 1) << 1) + (l15 >> 3);
      const int j = l15 & 7;
      #pragma unroll
      for (int r = 0; r < 4; ++r)
        ctx[(((tileC * 8 + sctx) * 4 + w) * 64 + (gctx << 4) + (g << 2) + r) * 8 + j]
            = f2b(oc[n2][r]);
    }
    __syncthreads();
  }

  {
    char* reg = (char*)smem + (w << 14);
    #pragma unroll
    for (int nt = 0; nt < 16; ++nt){
      unsigned off = ((l15 << 10) + (nt << 6) + (g << 4)) ^ ((l15 & 7) << 4);
      *(f32x4*)(reg + off) = am[nt];
    }
    __syncthreads();
    #pragma unroll
    for (int i2 = 0; i2 < 16; ++i2){
      unsigned fb = (tid << 4) + (i2 << 12);
      unsigned rowin = (fb >> 10) & 15;
      f32x4 v = *(const f32x4*)((char*)smem + (fb ^ ((rowin & 7) << 4)));
      unsigned row = fb >> 10;
      *(f32x4*)&am_out[((size_t)b * 4096 + q0 + row) * 256 + ((fb & 1023) >> 2)] = v;
    }
  }
#undef STG
}

// ---------------- fused tail: O-proj(+res)+LN -> M1(+GELU) -> M2(+res) ------
// Block = 1 tile (64 rows), 4 waves.
// Dynamic LDS = As(64x264 shorts = 33792B) + Ws(2x256x40 shorts = 40960B)
//             = 74752 B total (r14 bug: allocated only 66560 -> Ws[1] OOB).
// x held in registers across all three phases; A re-formed via As LDS bounce.
__global__ __launch_bounds__(256, 2) void tail_k(
    const short* __restrict__ ctxaf,
    const short* __restrict__ Wo, const short* __restrict__ Wm1,
    const short* __restrict__ Wm2,
    const float* __restrict__ b_o, const float* __restrict__ b_m1,
    const float* __restrict__ b_m2,
    const float* __restrict__ node,
    const float* __restrict__ lng, const float* __restrict__ lnb,
    float* __restrict__ outF)
{
  extern __shared__ __align__(16) short lds[];
  short (*As)[264] = (short(*)[264])lds;                    // 33792 B
  short (*Ws)[256][40] = (short(*)[256][40])(lds + 16896);  // 2 x 20480 B
  const int tid = threadIdx.x;
  const int tile = blockIdx.x;
  const int m0 = tile << 6;
  const int w = tid >> 6, lane = tid & 63;
  const int l15 = lane & 15, g = lane >> 4;
  const int row_l = (w << 4) + (g << 2);

  short8 afr[8];
  f32x4 acc[16];

#define RUN_GEMM(WPTR, PROLOG_DONE)                                                  \
  do{                                                                                \
    if (!(PROLOG_DONE)){                                                             \
      short8 w0[4];                                                                  \
      _Pragma("unroll")                                                              \
      for (int it = 0; it < 4; ++it)                                                 \
        w0[it] = *(const short8*)&(WPTR)[(size_t)((it << 6) + (tid >> 2)) * 256 + ((tid & 3) << 3)]; \
      _Pragma("unroll")                                                              \
      for (int it = 0; it < 4; ++it)                                                 \
        *(short8*)&Ws[0][(it << 6) + (tid >> 2)][(tid & 3) << 3] = w0[it];           \
      __syncthreads();                                                               \
      _Pragma("unroll")                                                              \
      for (int s = 0; s < 8; ++s)                                                    \
        afr[s] = *(const short8*)&As[(w << 4) + l15][(s << 5) + (g << 3)];           \
    }                                                                                \
    _Pragma("unroll")                                                                \
    for (int nt = 0; nt < 16; ++nt) acc[nt] = (f32x4){0.f, 0.f, 0.f, 0.f};           \
    int cur = 0;                                                                     \
    for (int s = 0; s < 8; ++s){                                                     \
      const int k0 = s << 5;                                                         \
      short8 wreg[4];                                                                \
      if (s < 7){                                                                    \
        _Pragma("unroll")                                                            \
        for (int it = 0; it < 4; ++it)                                               \
          wreg[it] = *(const short8*)&(WPTR)[(size_t)((it << 6) + (tid >> 2)) * 256 + k0 + 32 + ((tid & 3) << 3)]; \
      }                                                                              \
      const short8 af = afr[s];                                                      \
      _Pragma("unroll")                                                              \
      for (int nt = 0; nt < 16; ++nt){                                               \
        short8 bf = *(const short8*)&Ws[cur][(nt << 4) + l15][g << 3];               \
        acc[nt] = __builtin_amdgcn_mfma_f32_16x16x32_bf16(af, bf, acc[nt], 0, 0, 0); \
      }                                                                              \
      if (s < 7){                                                                    \
        _Pragma("unroll")                                                            \
        for (int it = 0; it < 4; ++it)                                               \
          *(short8*)&Ws[cur ^ 1][(it << 6) + (tid >> 2)][(tid & 3) << 3] = wreg[it]; \
      }                                                                              \
      __syncthreads();                                                               \
      cur ^= 1;                                                                      \
    }                                                                                \
  }while(0)

  // ---- phase O: A = ctx afrag (coalesced direct loads) ----
  #pragma unroll
  for (int s = 0; s < 8; ++s)
    afr[s] = *(const short8*)&ctxaf[((((size_t)tile << 3) + s) * 4 + w) * 512 + (lane << 3)];
  {
    short8 w0[4];
    #pragma unroll
    for (int it = 0; it < 4; ++it)
      w0[it] = *(const short8*)&Wo[(size_t)((it << 6) + (tid >> 2)) * 256 + ((tid & 3) << 3)];
    #pragma unroll
    for (int it = 0; it < 4; ++it)
      *(short8*)&Ws[0][(it << 6) + (tid >> 2)][(tid & 3) << 3] = w0[it];
  }
  __syncthreads();
  RUN_GEMM(Wo, 1);

  // x = acc + b_o + node (residual); keep in registers
  f32x4 xv[16];
  #pragma unroll
  for (int nt = 0; nt < 16; ++nt){
    const int col = (nt << 4) + l15;
    const float bv = b_o[col];
    #pragma unroll
    for (int r = 0; r < 4; ++r)
      xv[nt][r] = acc[nt][r] + bv + node[(size_t)(m0 + row_l + r) * 256 + col];
  }
  // LN(x) -> As (bf16)
  #pragma unroll
  for (int r = 0; r < 4; ++r){
    float s1 = 0.f, s2 = 0.f;
    #pragma unroll
    for (int nt = 0; nt < 16; ++nt){ float v = xv[nt][r]; s1 += v; s2 += v * v; }
    #pragma unroll
    for (int off = 1; off < 16; off <<= 1){ s1 += __shfl_xor(s1, off); s2 += __shfl_xor(s2, off); }
    const float mu = s1 * 0.00390625f;
    const float rs = rsqrtf(s2 * 0.00390625f - mu * mu + 1e-5f);
    #pragma unroll
    for (int nt = 0; nt < 16; ++nt){
      const int col = (nt << 4) + l15;
      As[row_l + r][col] = f2b((xv[nt][r] - mu) * rs * lng[col] + lnb[col]);
    }
  }
  // ---- phase M1 ----
  RUN_GEMM(Wm1, 0);
  // GELU(acc + b_m1) -> As
  #pragma unroll
  for (int nt = 0; nt < 16; ++nt){
    const int col = (nt << 4) + l15;
    const float bv = b_m1[col];
    #pragma unroll
    for (int r = 0; r < 4; ++r){
      float v = acc[nt][r] + bv;
      v = 0.5f * v * (1.0f + erff(v * 0.70710678118f));
      As[row_l + r][col] = f2b(v);
    }
  }
  // ---- phase M2 ----
  RUN_GEMM(Wm2, 0);
  #pragma unroll
  for (int nt = 0; nt < 16; ++nt){
    const int col = (nt << 4) + l15;
    const float bv = b_m2[col];
    #pragma unroll
    for (int r = 0; r < 4; ++r)
      outF[(size_t)(m0 + row_l + r) * 256 + col] = acc[nt][r] + bv + xv[nt][r];
  }
#undef RUN_GEMM
}

extern "C" void kernel_launch(void* const* d_in, const int* in_sizes, int n_in,
                              void* d_out, int out_size, void* d_ws, size_t ws_size,
                              hipStream_t stream)
{
  const float* node_emb = (const float*)d_in[0];
  const float* cluster  = (const float*)d_in[1];
  const float* cw       = (const float*)d_in[2];
  const float* ln_q_g   = (const float*)d_in[3];
  const float* ln_q_b   = (const float*)d_in[4];
  const float* ln_kv_g  = (const float*)d_in[5];
  const float* ln_kv_b  = (const float*)d_in[6];
  const float* ln_o_g   = (const float*)d_in[7];
  const float* ln_o_b   = (const float*)d_in[8];
  const float* W_q  = (const float*)d_in[9];  const float* b_q  = (const float*)d_in[10];
  const float* W_k  = (const float*)d_in[11]; const float* b_k  = (const float*)d_in[12];
  const float* W_v  = (const float*)d_in[13]; const float* b_v  = (const float*)d_in[14];
  const float* W_o  = (const float*)d_in[15]; const float* b_o  = (const float*)d_in[16];
  const float* W_m1 = (const float*)d_in[17]; const float* b_m1 = (const float*)d_in[18];
  const float* W_m2 = (const float*)d_in[19]; const float* b_m2 = (const float*)d_in[20];

  char* ws = (char*)d_ws;
  short* Wbf   = (short*)ws;                                   // 786,432 B row-major bf16
  short* bufA  = (short*)(ws + 786432);                        // 16.78 MB: ctx afrag
  short* bufB  = (short*)(ws + 786432 + 16777216);             // 16.78 MB: Q afrag
  short* kvin  = (short*)(ws + 786432 + 2 * 16777216);         // 1 MB
  short* kfrag = (short*)(ws + 786432 + 2 * 16777216 + 1048576);
  short* vfrag = (short*)(ws + 786432 + 2 * 16777216 + 2 * 1048576);

  float* outF = (float*)d_out;            // final out (written only by tail_k)
  float* amof = (float*)d_out + 8388608;  // attn_matrix

  hipFuncSetAttribute((const void*)attn_k, hipFuncAttributeMaxDynamicSharedMemorySize, 65536);
  hipFuncSetAttribute((const void*)tail_k, hipFuncAttributeMaxDynamicSharedMemorySize, 74752);

  cvt_w<<<1536, 256, 0, stream>>>(W_q, W_k, W_v, W_o, W_m1, W_m2, Wbf);
  ln_k<<<2048, 256, 0, stream>>>(cluster, ln_kv_g, ln_kv_b, kvin);
  // Q projection: fused input-LN, afrag output -> bufB
  gemmW<4,1><<<512, 256, 0, stream>>>(nullptr, node_emb, Wbf, b_q, bufB, ln_q_g, ln_q_b);
  // K / V projections -> kfrag / vfrag
  gemmW<1,0><<<32, 256, 0, stream>>>(kvin, nullptr, Wbf + 65536,  b_k, kfrag, nullptr, nullptr);
  gemmW<2,0><<<32, 256, 0, stream>>>(kvin, nullptr, Wbf + 131072, b_v, vfrag, nullptr, nullptr);
  // attention (ctx afrag -> bufA, attn_matrix -> d_out 2nd half)
  attn_k<<<dim3(64, 8), 256, 65536, stream>>>(bufB, kfrag, vfrag, cw, bufA, amof);
  // fused tail: O(+res)+LN -> M1(+GELU) -> M2(+res) -> out
  tail_k<<<512, 256, 74752, stream>>>(bufA, Wbf + 196608, Wbf + 262144, Wbf + 327680,
      b_o, b_m1, b_m2, node_emb, ln_o_g, ln_o_b, outF);
}

// Round 16
// 123.512 us; speedup vs baseline: 1.7837x; 1.0448x over previous
//
#include <hip/hip_runtime.h>
#include <math.h>

typedef __attribute__((ext_vector_type(8))) short short8;
typedef __attribute__((ext_vector_type(4))) float f32x4;
typedef __attribute__((ext_vector_type(2))) unsigned int u32x2;

#define AS1 __attribute__((address_space(1)))
#define AS3 __attribute__((address_space(3)))

__device__ __forceinline__ float b2f(short s){
  return __uint_as_float(((unsigned int)(unsigned short)s) << 16);
}
__device__ __forceinline__ short f2b(float f){
  unsigned int u = __float_as_uint(f);
  u = (u + 0x7fffu + ((u >> 16) & 1u)) >> 16;
  return (short)u;
}
__device__ __forceinline__ unsigned pk2(float lo, float hi){
  return ((unsigned)(unsigned short)f2b(hi) << 16) | (unsigned)(unsigned short)f2b(lo);
}
__device__ __forceinline__ float ulo(unsigned u){ return __uint_as_float(u << 16); }
__device__ __forceinline__ float uhi(unsigned u){ return __uint_as_float(u & 0xffff0000u); }

// ---------------- weight f32 -> bf16 ----------------
// dst: row-major (6 mats). dstS: stage-order [s][row][g][8] copy of mats 3..5
// (W_o, W_m1, W_m2) for the tail's global_load_lds staging (r10/r11-verified).
__global__ __launch_bounds__(256) void cvt_w(
    const float* __restrict__ s0, const float* __restrict__ s1,
    const float* __restrict__ s2, const float* __restrict__ s3,
    const float* __restrict__ s4, const float* __restrict__ s5,
    short* __restrict__ dst, short* __restrict__ dstS)
{
  const float* srcs[6] = {s0, s1, s2, s3, s4, s5};
  int i = blockIdx.x * 256 + threadIdx.x;       // 6*65536 total
  int mat = i >> 16, rc = i & 65535;
  short v = f2b(srcs[mat][rc]);
  dst[i] = v;
  if (mat >= 3){
    int row = rc >> 8, col = rc & 255;
    int d2 = (mat - 3) * 65536 + ((col >> 5) << 13) + (row << 5)
           + (((col >> 3) & 3) << 3) + (col & 7);
    dstS[d2] = v;
  }
}

// ---------------- LayerNorm: f32 in, bf16 out (kv path) ----------------
__global__ __launch_bounds__(256) void ln_k(
    const float* __restrict__ x, const float* __restrict__ g,
    const float* __restrict__ bta, short* __restrict__ y)
{
  const int row = blockIdx.x, t = threadIdx.x;
  const size_t base = (size_t)row * 256;
  float v = x[base + t];
  float s1 = v, s2 = v * v;
  #pragma unroll
  for (int off = 32; off; off >>= 1){ s1 += __shfl_down(s1, off); s2 += __shfl_down(s2, off); }
  __shared__ float a1[4], a2[4];
  __shared__ float mu_s, rs_s;
  if ((t & 63) == 0){ a1[t >> 6] = s1; a2[t >> 6] = s2; }
  __syncthreads();
  if (t == 0){
    float S1 = a1[0] + a1[1] + a1[2] + a1[3];
    float S2 = a2[0] + a2[1] + a2[2] + a2[3];
    float mu = S1 * 0.00390625f;
    float var = S2 * 0.00390625f - mu * mu;
    mu_s = mu; rs_s = rsqrtf(var + 1e-5f);
  }
  __syncthreads();
  y[base + t] = f2b((v - mu_s) * rs_s * g[t] + bta[t]);
}

// ---------------- wide GEMM (r8-proven body): C = A @ W^T + b ----------------
template<int OT, int LNA>
__global__ __launch_bounds__(256, 2) void gemmW(
    const short* __restrict__ A, const float* __restrict__ Af,
    const short* __restrict__ W, const float* __restrict__ bias,
    short* __restrict__ outB,
    const float* __restrict__ lnag, const float* __restrict__ lnab)
{
  __shared__ short As[64][264];
  __shared__ short Ws[2][256][40];
  const int tid = threadIdx.x;
  const int m0 = blockIdx.x << 6;
  const int w = tid >> 6, lane = tid & 63;
  const int l15 = lane & 15, g = lane >> 4;

  if (LNA){
    const int row = tid >> 2, c0 = (tid & 3) << 6;
    float vv[64];
    const float* src = &Af[(size_t)(m0 + row) * 256 + c0];
    #pragma unroll
    for (int i = 0; i < 16; ++i) *(f32x4*)&vv[4 * i] = *(const f32x4*)&src[4 * i];
    float s1 = 0.f, s2 = 0.f;
    #pragma unroll
    for (int i = 0; i < 64; ++i){ s1 += vv[i]; s2 += vv[i] * vv[i]; }
    s1 += __shfl_xor(s1, 1); s2 += __shfl_xor(s2, 1);
    s1 += __shfl_xor(s1, 2); s2 += __shfl_xor(s2, 2);
    const float mu = s1 * 0.00390625f;
    const float rs = rsqrtf(s2 * 0.00390625f - mu * mu + 1e-5f);
    #pragma unroll
    for (int i = 0; i < 8; ++i){
      f32x4 gv0 = *(const f32x4*)&lnag[c0 + 8 * i];
      f32x4 gv1 = *(const f32x4*)&lnag[c0 + 8 * i + 4];
      f32x4 bv0 = *(const f32x4*)&lnab[c0 + 8 * i];
      f32x4 bv1 = *(const f32x4*)&lnab[c0 + 8 * i + 4];
      short8 o;
      #pragma unroll
      for (int j = 0; j < 4; ++j) o[j] = f2b((vv[8 * i + j] - mu) * rs * gv0[j] + bv0[j]);
      #pragma unroll
      for (int j = 0; j < 4; ++j) o[4 + j] = f2b((vv[8 * i + 4 + j] - mu) * rs * gv1[j] + bv1[j]);
      *(short8*)&As[row][c0 + 8 * i] = o;
    }
  } else {
    #pragma unroll
    for (int it = 0; it < 8; ++it){
      int idx = tid + (it << 8);
      int row = idx >> 5, c = (idx & 31) << 3;
      *(short8*)&As[row][c] = *(const short8*)&A[(size_t)(m0 + row) * 256 + c];
    }
  }
  #pragma unroll
  for (int it = 0; it < 4; ++it){
    int row = (it << 6) + (tid >> 2), c = (tid & 3) << 3;
    *(short8*)&Ws[0][row][c] = *(const short8*)&W[(size_t)row * 256 + c];
  }
  __syncthreads();

  f32x4 acc[16];
  #pragma unroll
  for (int nt = 0; nt < 16; ++nt) acc[nt] = {0.f, 0.f, 0.f, 0.f};

  int cur = 0;
  for (int s = 0; s < 8; ++s){
    const int k0 = s << 5;
    short8 wreg[4];
    if (s < 7){
      #pragma unroll
      for (int it = 0; it < 4; ++it)
        wreg[it] = *(const short8*)&W[(size_t)((it << 6) + (tid >> 2)) * 256 + k0 + 32 + ((tid & 3) << 3)];
    }
    short8 af = *(const short8*)&As[(w << 4) + l15][k0 + (g << 3)];
    #pragma unroll
    for (int nt = 0; nt < 16; ++nt){
      short8 bf = *(const short8*)&Ws[cur][(nt << 4) + l15][g << 3];
      acc[nt] = __builtin_amdgcn_mfma_f32_16x16x32_bf16(af, bf, acc[nt], 0, 0, 0);
    }
    if (s < 7){
      #pragma unroll
      for (int it = 0; it < 4; ++it)
        *(short8*)&Ws[cur ^ 1][(it << 6) + (tid >> 2)][(tid & 3) << 3] = wreg[it];
    }
    __syncthreads();
    cur ^= 1;
  }

  const int row_l = (w << 4) + (g << 2);
  #pragma unroll
  for (int nt = 0; nt < 16; ++nt){
    const int col = (nt << 4) + l15;
    const float bv = bias[col];
    #pragma unroll
    for (int r = 0; r < 4; ++r){
      const int m = m0 + row_l + r;
      float v = acc[nt][r] + bv;
      if (OT == 1){   // kfrag
        const int b_ = m >> 8, kvr = m & 255;
        const int knt = kvr >> 4, kl = kvr & 15;
        const int h = col >> 6, half = (col >> 5) & 1, kg = (col >> 3) & 3, kj = col & 7;
        outB[(((((size_t)(b_ * 4 + h) * 16 + knt) * 2 + half) * 4 + kg) * 16 + kl) * 8 + kj] = f2b(v);
      }
      if (OT == 2){   // vfrag
        const int b_ = m >> 8, kvj = m & 255;
        const int jp = (kvj & ~31) | (((kvj >> 2) & 3) << 3) | (((kvj >> 4) & 1) << 2) | (kvj & 3);
        const int h = col >> 6, dp = col & 63;
        const int kk = jp >> 5, vg = (jp >> 3) & 3, vj = jp & 7;
        const int vn2 = dp >> 4, vl = dp & 15;
        outB[(((((size_t)(b_ * 4 + h) * 8 + kk) * 4 + vn2) * 4 + vg) * 16 + vl) * 8 + vj] = f2b(v);
      }
      if (OT == 4){   // standard afrag
        outB[((((size_t)blockIdx.x * 8 + (col >> 5)) * 4 + w) * 64
              + (((col >> 3) & 3) << 4) + (g << 2) + r) * 8 + (col & 7)] = f2b(v);
      }
    }
  }
}

// ---------------- fused MFMA attention (r12-proven, verbatim) ----------------
__global__ __launch_bounds__(256, 2) void attn_k(
    const short* __restrict__ Qf, const short* __restrict__ Kf,
    const short* __restrict__ Vf, const float* __restrict__ cw,
    short* __restrict__ ctx, float* __restrict__ am_out)
{
  extern __shared__ __align__(16) short smem[];   // 32768 shorts = 64KB
  short* Kl = smem;
  short* Vl = smem + 16384;
  const int b = blockIdx.y;
  const int q0 = blockIdx.x << 6;
  const int tid = threadIdx.x;
  const int w = tid >> 6, lane = tid & 63;
  const int l15 = lane & 15, g = lane >> 4;
  const size_t qw = (size_t)b * 4096 + q0 + (w << 4);
  const size_t qblk = qw >> 4;
  const size_t tileQ = qblk >> 2;
  const int wQ = (int)(qblk & 3);
  const size_t tileC = (size_t)b * 64 + blockIdx.x;

#define STG(dst_, src_) do{ _Pragma("unroll")                                        \
  for (int it_ = 0; it_ < 8; ++it_){ int c_ = (it_ << 8) + tid;                      \
    __builtin_amdgcn_global_load_lds((const AS1 void*)((src_) + (c_ << 3)),          \
                                     (AS3 void*)((dst_) + (c_ << 3)), 16, 0, 0); } }while(0)

  unsigned cwp[16][2];
  f32x4 am[16];
  {
    char* reg = (char*)smem + (w << 13);
    #pragma unroll
    for (int j = 0; j < 16; ++j){
      f32x4 v = *(const f32x4*)&cw[(qw + j) * 256 + (lane << 2)];
      u32x2 d = { pk2(v[0], v[1]), pk2(v[2], v[3]) };
      unsigned off = ((j << 9) + (lane << 3)) ^ ((j & 7) << 4);
      *(u32x2*)(reg + off) = d;
    }
    __syncthreads();
    #pragma unroll
    for (int nt = 0; nt < 16; ++nt){
      unsigned base = ((l15 << 9) + (nt << 5) + (g << 3)) ^ ((l15 & 7) << 4);
      cwp[nt][0] = *(const unsigned*)(reg + base);
      cwp[nt][1] = *(const unsigned*)(reg + base + 4);
      am[nt] = {0.f, 0.f, 0.f, 0.f};
    }
    __syncthreads();
  }

  STG(Kl, Kf + ((size_t)(b * 4) << 14));
  __syncthreads();

  for (int h = 0; h < 4; ++h){
    STG(Vl, Vf + ((size_t)(b * 4 + h) << 14));
    short8 qf0 = *(const short8*)&Qf[(((tileQ * 8 + (h << 1)) * 4 + wQ) * 64 + lane) * 8];
    short8 qf1 = *(const short8*)&Qf[(((tileQ * 8 + (h << 1) + 1) * 4 + wQ) * 64 + lane) * 8];

    f32x4 acc[16];
    #pragma unroll
    for (int nt = 0; nt < 16; ++nt) acc[nt] = {0.f, 0.f, 0.f, 0.f};
    #pragma unroll
    for (int nt = 0; nt < 16; ++nt){
      short8 kf0 = *(const short8*)&Kl[(nt << 10) + (lane << 3)];
      acc[nt] = __builtin_amdgcn_mfma_f32_16x16x32_bf16(kf0, qf0, acc[nt], 0, 0, 0);
      short8 kf1 = *(const short8*)&Kl[(nt << 10) + 512 + (lane << 3)];
      acc[nt] = __builtin_amdgcn_mfma_f32_16x16x32_bf16(kf1, qf1, acc[nt], 0, 0, 0);
    }
    __syncthreads();
    if (h < 3) STG(Kl, Kf + ((size_t)(b * 4 + h + 1) << 14));

    float mx = -3.4e38f;
    #pragma unroll
    for (int nt = 0; nt < 16; ++nt){
      float c0 = __uint_as_float(cwp[nt][0] << 16);
      float c1 = __uint_as_float(cwp[nt][0] & 0xffff0000u);
      float c2 = __uint_as_float(cwp[nt][1] << 16);
      float c3 = __uint_as_float(cwp[nt][1] & 0xffff0000u);
      acc[nt][0] = acc[nt][0] * 0.125f + c0;
      acc[nt][1] = acc[nt][1] * 0.125f + c1;
      acc[nt][2] = acc[nt][2] * 0.125f + c2;
      acc[nt][3] = acc[nt][3] * 0.125f + c3;
      mx = fmaxf(mx, fmaxf(fmaxf(acc[nt][0], acc[nt][1]), fmaxf(acc[nt][2], acc[nt][3])));
    }
    mx = fmaxf(mx, __shfl_xor(mx, 16));
    mx = fmaxf(mx, __shfl_xor(mx, 32));
    float sm = 0.f;
    #pragma unroll
    for (int nt = 0; nt < 16; ++nt){
      #pragma unroll
      for (int r = 0; r < 4; ++r){
        float e = __expf(acc[nt][r] - mx);
        acc[nt][r] = e; sm += e;
      }
    }
    sm += __shfl_xor(sm, 16);
    sm += __shfl_xor(sm, 32);
    float inv = 1.f / sm;
    #pragma unroll
    for (int nt = 0; nt < 16; ++nt){
      #pragma unroll
      for (int r = 0; r < 4; ++r){
        float p = acc[nt][r] * inv;
        acc[nt][r] = p;
        am[nt][r] += 0.25f * p;
      }
    }
    f32x4 oc[4] = {{0,0,0,0},{0,0,0,0},{0,0,0,0},{0,0,0,0}};
    #pragma unroll
    for (int kk = 0; kk < 8; ++kk){
      union { short8 s; unsigned u[4]; } pa;
      pa.u[0] = pk2(acc[2 * kk][0],     acc[2 * kk][1]);
      pa.u[1] = pk2(acc[2 * kk][2],     acc[2 * kk][3]);
      pa.u[2] = pk2(acc[2 * kk + 1][0], acc[2 * kk + 1][1]);
      pa.u[3] = pk2(acc[2 * kk + 1][2], acc[2 * kk + 1][3]);
      #pragma unroll
      for (int n2 = 0; n2 < 4; ++n2){
        short8 vb = *(const short8*)&Vl[(((kk << 2) + n2) << 9) + (lane << 3)];
        oc[n2] = __builtin_amdgcn_mfma_f32_16x16x32_bf16(pa.s, vb, oc[n2], 0, 0, 0);
      }
    }
    #pragma unroll
    for (int n2 = 0; n2 < 4; ++n2){
      const int sctx = (h << 1) + (n2 >> 1);
      const int gctx = ((n2 & 1) << 1) + (l15 >> 3);
      const int j = l15 & 7;
      #pragma unroll
      for (int r = 0; r < 4; ++r)
        ctx[(((tileC * 8 + sctx) * 4 + w) * 64 + (gctx << 4) + (g << 2) + r) * 8 + j]
            = f2b(oc[n2][r]);
    }
    __syncthreads();
  }

  {
    char* reg = (char*)smem + (w << 14);
    #pragma unroll
    for (int nt = 0; nt < 16; ++nt){
      unsigned off = ((l15 << 10) + (nt << 6) + (g << 4)) ^ ((l15 & 7) << 4);
      *(f32x4*)(reg + off) = am[nt];
    }
    __syncthreads();
    #pragma unroll
    for (int i2 = 0; i2 < 16; ++i2){
      unsigned fb = (tid << 4) + (i2 << 12);
      unsigned rowin = (fb >> 10) & 15;
      f32x4 v = *(const f32x4*)((char*)smem + (fb ^ ((rowin & 7) << 4)));
      unsigned row = fb >> 10;
      *(f32x4*)&am_out[((size_t)b * 4096 + q0 + row) * 256 + ((fb & 1023) >> 2)] = v;
    }
  }
#undef STG
}

// ---------------- fused tail: O-proj(+res)+LN -> M1(+GELU) -> M2(+res) ------
// Block = 1 tile (64 rows), 4 waves. LDS 66560B = As(33792, XOR-swizzled)
// + Ws dbuf(2x16384, linear, global_load_lds-staged from stage-order Wst).
// x packed bf16 in 32 regs; af read per-step from As; no wreg round-trip.
// Target: live set < 128 VGPR (no spill at the 128 tier).
__global__ __launch_bounds__(256, 2) void tail_k(
    const short* __restrict__ ctxaf, const short* __restrict__ Wst,
    const float* __restrict__ b_o, const float* __restrict__ b_m1,
    const float* __restrict__ b_m2, const float* __restrict__ node,
    const float* __restrict__ lng, const float* __restrict__ lnb,
    float* __restrict__ outF)
{
  extern __shared__ __align__(16) short lds[];
  short* Ws0 = lds + 16896;   // As occupies [0, 16896) shorts (64*264)
  short* Ws1 = Ws0 + 8192;
  const int tid = threadIdx.x;
  const int tile = blockIdx.x;
  const int m0 = tile << 6;
  const int w = tid >> 6, lane = tid & 63;
  const int l15 = lane & 15, g = lane >> 4;
  const int row_l = (w << 4) + (g << 2);

  // swizzled As accessors (write scalar short, read 16B chunk)
#define ASW(row_, col_) (*(short*)((char*)lds + (row_) * 528 + ((((col_) << 1)) ^ (((row_) & 7) << 4))))
#define ASR8(row_, boff_) (*(const short8*)((char*)lds + (row_) * 528 + ((boff_) ^ (((row_) & 7) << 4))))
  // stage one 32-k slice of a stage-order weight mat into dst (16KB, coalesced)
#define STGW(dst_, wmat_, s_) do{ _Pragma("unroll")                                  \
  for (int it_ = 0; it_ < 4; ++it_){ int c_ = (it_ << 8) + tid;                      \
    __builtin_amdgcn_global_load_lds(                                               \
        (const AS1 void*)((wmat_) + ((size_t)(s_) << 13) + (c_ << 3)),              \
        (AS3 void*)((dst_) + (c_ << 3)), 16, 0, 0); } }while(0)

  f32x4 acc[16];

  // ================= phase O: A = ctx afrag (hoisted regs) =================
  STGW(Ws0, Wst, 0);
  short8 afr[8];
  #pragma unroll
  for (int s = 0; s < 8; ++s)
    afr[s] = *(const short8*)&ctxaf[((((size_t)tile << 3) + s) * 4 + w) * 512 + (lane << 3)];
  __syncthreads();
  #pragma unroll
  for (int nt = 0; nt < 16; ++nt) acc[nt] = {0.f, 0.f, 0.f, 0.f};
  {
    int cur = 0;
    #pragma unroll
    for (int s = 0; s < 8; ++s){
      short* rbuf = cur ? Ws1 : Ws0;
      short* sbuf = cur ? Ws0 : Ws1;
      if (s < 7) STGW(sbuf, Wst, s + 1);
      const short8 af = afr[s];
      #pragma unroll
      for (int nt = 0; nt < 16; ++nt){
        short8 bf = *(const short8*)&rbuf[((nt << 4) + l15) * 32 + (g << 3)];
        acc[nt] = __builtin_amdgcn_mfma_f32_16x16x32_bf16(af, bf, acc[nt], 0, 0, 0);
      }
      __syncthreads();
      cur ^= 1;
    }
  }

  // x = acc + b_o + node, packed bf16 (32 regs); LN(x) -> As (swizzled)
  unsigned xvp[16][2];
  #pragma unroll
  for (int nt = 0; nt < 16; ++nt){
    const int col = (nt << 4) + l15;
    const float bv = b_o[col];
    float x0 = acc[nt][0] + bv + node[(size_t)(m0 + row_l + 0) * 256 + col];
    float x1 = acc[nt][1] + bv + node[(size_t)(m0 + row_l + 1) * 256 + col];
    float x2 = acc[nt][2] + bv + node[(size_t)(m0 + row_l + 2) * 256 + col];
    float x3 = acc[nt][3] + bv + node[(size_t)(m0 + row_l + 3) * 256 + col];
    xvp[nt][0] = pk2(x0, x1);
    xvp[nt][1] = pk2(x2, x3);
  }
  #pragma unroll
  for (int r = 0; r < 4; ++r){
    float s1 = 0.f, s2 = 0.f;
    #pragma unroll
    for (int nt = 0; nt < 16; ++nt){
      float v = (r == 0) ? ulo(xvp[nt][0]) : (r == 1) ? uhi(xvp[nt][0])
              : (r == 2) ? ulo(xvp[nt][1]) : uhi(xvp[nt][1]);
      s1 += v; s2 += v * v;
    }
    #pragma unroll
    for (int off = 1; off < 16; off <<= 1){ s1 += __shfl_xor(s1, off); s2 += __shfl_xor(s2, off); }
    const float mu = s1 * 0.00390625f;
    const float rs = rsqrtf(s2 * 0.00390625f - mu * mu + 1e-5f);
    #pragma unroll
    for (int nt = 0; nt < 16; ++nt){
      const int col = (nt << 4) + l15;
      float v = (r == 0) ? ulo(xvp[nt][0]) : (r == 1) ? uhi(xvp[nt][0])
              : (r == 2) ? ulo(xvp[nt][1]) : uhi(xvp[nt][1]);
      ASW(row_l + r, col) = f2b((v - mu) * rs * lng[col] + lnb[col]);
    }
  }

  // ================= phase M1 (af per-step from As) =================
  {
    const short* Wm1 = Wst + 65536;
    STGW(Ws0, Wm1, 0);
    __syncthreads();                     // As writes + slice0 visible
    #pragma unroll
    for (int nt = 0; nt < 16; ++nt) acc[nt] = {0.f, 0.f, 0.f, 0.f};
    int cur = 0;
    #pragma unroll
    for (int s = 0; s < 8; ++s){
      short* rbuf = cur ? Ws1 : Ws0;
      short* sbuf = cur ? Ws0 : Ws1;
      if (s < 7) STGW(sbuf, Wm1, s + 1);
      const short8 af = ASR8((w << 4) + l15, (s << 6) + (g << 4));
      #pragma unroll
      for (int nt = 0; nt < 16; ++nt){
        short8 bf = *(const short8*)&rbuf[((nt << 4) + l15) * 32 + (g << 3)];
        acc[nt] = __builtin_amdgcn_mfma_f32_16x16x32_bf16(af, bf, acc[nt], 0, 0, 0);
      }
      __syncthreads();
      cur ^= 1;
    }
  }
  // GELU(acc + b_m1) -> As (swizzled)
  #pragma unroll
  for (int nt = 0; nt < 16; ++nt){
    const int col = (nt << 4) + l15;
    const float bv = b_m1[col];
    #pragma unroll
    for (int r = 0; r < 4; ++r){
      float v = acc[nt][r] + bv;
      v = 0.5f * v * (1.0f + erff(v * 0.70710678118f));
      ASW(row_l + r, col) = f2b(v);
    }
  }

  // ================= phase M2 =================
  {
    const short* Wm2 = Wst + 131072;
    STGW(Ws0, Wm2, 0);
    __syncthreads();
    #pragma unroll
    for (int nt = 0; nt < 16; ++nt) acc[nt] = {0.f, 0.f, 0.f, 0.f};
    int cur = 0;
    #pragma unroll
    for (int s = 0; s < 8; ++s){
      short* rbuf = cur ? Ws1 : Ws0;
      short* sbuf = cur ? Ws0 : Ws1;
      if (s < 7) STGW(sbuf, Wm2, s + 1);
      const short8 af = ASR8((w << 4) + l15, (s << 6) + (g << 4));
      #pragma unroll
      for (int nt = 0; nt < 16; ++nt){
        short8 bf = *(const short8*)&rbuf[((nt << 4) + l15) * 32 + (g << 3)];
        acc[nt] = __builtin_amdgcn_mfma_f32_16x16x32_bf16(af, bf, acc[nt], 0, 0, 0);
      }
      __syncthreads();
      cur ^= 1;
    }
  }
  // out = acc + b_m2 + x
  #pragma unroll
  for (int nt = 0; nt < 16; ++nt){
    const int col = (nt << 4) + l15;
    const float bv = b_m2[col];
    #pragma unroll
    for (int r = 0; r < 4; ++r){
      float xr = (r == 0) ? ulo(xvp[nt][0]) : (r == 1) ? uhi(xvp[nt][0])
               : (r == 2) ? ulo(xvp[nt][1]) : uhi(xvp[nt][1]);
      outF[(size_t)(m0 + row_l + r) * 256 + col] = acc[nt][r] + bv + xr;
    }
  }
#undef ASW
#undef ASR8
#undef STGW
}

extern "C" void kernel_launch(void* const* d_in, const int* in_sizes, int n_in,
                              void* d_out, int out_size, void* d_ws, size_t ws_size,
                              hipStream_t stream)
{
  const float* node_emb = (const float*)d_in[0];
  const float* cluster  = (const float*)d_in[1];
  const float* cw       = (const float*)d_in[2];
  const float* ln_q_g   = (const float*)d_in[3];
  const float* ln_q_b   = (const float*)d_in[4];
  const float* ln_kv_g  = (const float*)d_in[5];
  const float* ln_kv_b  = (const float*)d_in[6];
  const float* ln_o_g   = (const float*)d_in[7];
  const float* ln_o_b   = (const float*)d_in[8];
  const float* W_q  = (const float*)d_in[9];  const float* b_q  = (const float*)d_in[10];
  const float* W_k  = (const float*)d_in[11]; const float* b_k  = (const float*)d_in[12];
  const float* W_v  = (const float*)d_in[13]; const float* b_v  = (const float*)d_in[14];
  const float* W_o  = (const float*)d_in[15]; const float* b_o  = (const float*)d_in[16];
  const float* W_m1 = (const float*)d_in[17]; const float* b_m1 = (const float*)d_in[18];
  const float* W_m2 = (const float*)d_in[19]; const float* b_m2 = (const float*)d_in[20];

  char* ws = (char*)d_ws;
  short* Wbf   = (short*)ws;                                   // 786,432 B row-major (6 mats)
  short* Wst   = (short*)(ws + 786432);                        // 393,216 B stage-order (O,M1,M2)
  short* bufA  = (short*)(ws + 1179648);                       // 16.78 MB: ctx afrag
  short* bufB  = (short*)(ws + 1179648 + 16777216);            // 16.78 MB: Q afrag
  short* kvin  = (short*)(ws + 1179648 + 2 * 16777216);        // 1 MB
  short* kfrag = (short*)(ws + 1179648 + 2 * 16777216 + 1048576);
  short* vfrag = (short*)(ws + 1179648 + 2 * 16777216 + 2 * 1048576);

  float* outF = (float*)d_out;            // final out (written only by tail_k)
  float* amof = (float*)d_out + 8388608;  // attn_matrix

  hipFuncSetAttribute((const void*)attn_k, hipFuncAttributeMaxDynamicSharedMemorySize, 65536);
  hipFuncSetAttribute((const void*)tail_k, hipFuncAttributeMaxDynamicSharedMemorySize, 66560);

  cvt_w<<<1536, 256, 0, stream>>>(W_q, W_k, W_v, W_o, W_m1, W_m2, Wbf, Wst);
  ln_k<<<2048, 256, 0, stream>>>(cluster, ln_kv_g, ln_kv_b, kvin);
  // Q projection: fused input-LN, afrag output -> bufB
  gemmW<4,1><<<512, 256, 0, stream>>>(nullptr, node_emb, Wbf, b_q, bufB, ln_q_g, ln_q_b);
  // K / V projections -> kfrag / vfrag
  gemmW<1,0><<<32, 256, 0, stream>>>(kvin, nullptr, Wbf + 65536,  b_k, kfrag, nullptr, nullptr);
  gemmW<2,0><<<32, 256, 0, stream>>>(kvin, nullptr, Wbf + 131072, b_v, vfrag, nullptr, nullptr);
  // attention (ctx afrag -> bufA, attn_matrix -> d_out 2nd half)
  attn_k<<<dim3(64, 8), 256, 65536, stream>>>(bufB, kfrag, vfrag, cw, bufA, amof);
  // fused tail: O(+res)+LN -> M1(+GELU) -> M2(+res) -> out
  tail_k<<<512, 256, 66560, stream>>>(bufA, Wst, b_o, b_m1, b_m2,
      node_emb, ln_o_g, ln_o_b, outF);
}

// Round 17
// 121.871 us; speedup vs baseline: 1.8077x; 1.0135x over previous
//
#include <hip/hip_runtime.h>
#include <math.h>

typedef __attribute__((ext_vector_type(8))) short short8;
typedef __attribute__((ext_vector_type(4))) float f32x4;
typedef __attribute__((ext_vector_type(2))) unsigned int u32x2;

#define AS1 __attribute__((address_space(1)))
#define AS3 __attribute__((address_space(3)))

__device__ __forceinline__ float b2f(short s){
  return __uint_as_float(((unsigned int)(unsigned short)s) << 16);
}
__device__ __forceinline__ short f2b(float f){
  unsigned int u = __float_as_uint(f);
  u = (u + 0x7fffu + ((u >> 16) & 1u)) >> 16;
  return (short)u;
}
__device__ __forceinline__ unsigned pk2(float lo, float hi){
  return ((unsigned)(unsigned short)f2b(hi) << 16) | (unsigned)(unsigned short)f2b(lo);
}
__device__ __forceinline__ float ulo(unsigned u){ return __uint_as_float(u << 16); }
__device__ __forceinline__ float uhi(unsigned u){ return __uint_as_float(u & 0xffff0000u); }

// ---------------- weight f32 -> bf16 ----------------
// dst: row-major (6 mats). dstS: stage-order [s][row][g][8] copy of mats 3..5
// (W_o, W_m1, W_m2) for the tail's global_load_lds staging.
__global__ __launch_bounds__(256) void cvt_w(
    const float* __restrict__ s0, const float* __restrict__ s1,
    const float* __restrict__ s2, const float* __restrict__ s3,
    const float* __restrict__ s4, const float* __restrict__ s5,
    short* __restrict__ dst, short* __restrict__ dstS)
{
  const float* srcs[6] = {s0, s1, s2, s3, s4, s5};
  int i = blockIdx.x * 256 + threadIdx.x;       // 6*65536 total
  int mat = i >> 16, rc = i & 65535;
  short v = f2b(srcs[mat][rc]);
  dst[i] = v;
  if (mat >= 3){
    int row = rc >> 8, col = rc & 255;
    int d2 = (mat - 3) * 65536 + ((col >> 5) << 13) + (row << 5)
           + (((col >> 3) & 3) << 3) + (col & 7);
    dstS[d2] = v;
  }
}

// ---------------- LayerNorm: f32 in, bf16 out (kv path) ----------------
__global__ __launch_bounds__(256) void ln_k(
    const float* __restrict__ x, const float* __restrict__ g,
    const float* __restrict__ bta, short* __restrict__ y)
{
  const int row = blockIdx.x, t = threadIdx.x;
  const size_t base = (size_t)row * 256;
  float v = x[base + t];
  float s1 = v, s2 = v * v;
  #pragma unroll
  for (int off = 32; off; off >>= 1){ s1 += __shfl_down(s1, off); s2 += __shfl_down(s2, off); }
  __shared__ float a1[4], a2[4];
  __shared__ float mu_s, rs_s;
  if ((t & 63) == 0){ a1[t >> 6] = s1; a2[t >> 6] = s2; }
  __syncthreads();
  if (t == 0){
    float S1 = a1[0] + a1[1] + a1[2] + a1[3];
    float S2 = a2[0] + a2[1] + a2[2] + a2[3];
    float mu = S1 * 0.00390625f;
    float var = S2 * 0.00390625f - mu * mu;
    mu_s = mu; rs_s = rsqrtf(var + 1e-5f);
  }
  __syncthreads();
  y[base + t] = f2b((v - mu_s) * rs_s * g[t] + bta[t]);
}

// ---------------- wide GEMM (r8-proven body): C = A @ W^T + b ----------------
template<int OT, int LNA>
__global__ __launch_bounds__(256, 2) void gemmW(
    const short* __restrict__ A, const float* __restrict__ Af,
    const short* __restrict__ W, const float* __restrict__ bias,
    short* __restrict__ outB,
    const float* __restrict__ lnag, const float* __restrict__ lnab)
{
  __shared__ short As[64][264];
  __shared__ short Ws[2][256][40];
  const int tid = threadIdx.x;
  const int m0 = blockIdx.x << 6;
  const int w = tid >> 6, lane = tid & 63;
  const int l15 = lane & 15, g = lane >> 4;

  if (LNA){
    const int row = tid >> 2, c0 = (tid & 3) << 6;
    float vv[64];
    const float* src = &Af[(size_t)(m0 + row) * 256 + c0];
    #pragma unroll
    for (int i = 0; i < 16; ++i) *(f32x4*)&vv[4 * i] = *(const f32x4*)&src[4 * i];
    float s1 = 0.f, s2 = 0.f;
    #pragma unroll
    for (int i = 0; i < 64; ++i){ s1 += vv[i]; s2 += vv[i] * vv[i]; }
    s1 += __shfl_xor(s1, 1); s2 += __shfl_xor(s2, 1);
    s1 += __shfl_xor(s1, 2); s2 += __shfl_xor(s2, 2);
    const float mu = s1 * 0.00390625f;
    const float rs = rsqrtf(s2 * 0.00390625f - mu * mu + 1e-5f);
    #pragma unroll
    for (int i = 0; i < 8; ++i){
      f32x4 gv0 = *(const f32x4*)&lnag[c0 + 8 * i];
      f32x4 gv1 = *(const f32x4*)&lnag[c0 + 8 * i + 4];
      f32x4 bv0 = *(const f32x4*)&lnab[c0 + 8 * i];
      f32x4 bv1 = *(const f32x4*)&lnab[c0 + 8 * i + 4];
      short8 o;
      #pragma unroll
      for (int j = 0; j < 4; ++j) o[j] = f2b((vv[8 * i + j] - mu) * rs * gv0[j] + bv0[j]);
      #pragma unroll
      for (int j = 0; j < 4; ++j) o[4 + j] = f2b((vv[8 * i + 4 + j] - mu) * rs * gv1[j] + bv1[j]);
      *(short8*)&As[row][c0 + 8 * i] = o;
    }
  } else {
    #pragma unroll
    for (int it = 0; it < 8; ++it){
      int idx = tid + (it << 8);
      int row = idx >> 5, c = (idx & 31) << 3;
      *(short8*)&As[row][c] = *(const short8*)&A[(size_t)(m0 + row) * 256 + c];
    }
  }
  #pragma unroll
  for (int it = 0; it < 4; ++it){
    int row = (it << 6) + (tid >> 2), c = (tid & 3) << 3;
    *(short8*)&Ws[0][row][c] = *(const short8*)&W[(size_t)row * 256 + c];
  }
  __syncthreads();

  f32x4 acc[16];
  #pragma unroll
  for (int nt = 0; nt < 16; ++nt) acc[nt] = {0.f, 0.f, 0.f, 0.f};

  int cur = 0;
  for (int s = 0; s < 8; ++s){
    const int k0 = s << 5;
    short8 wreg[4];
    if (s < 7){
      #pragma unroll
      for (int it = 0; it < 4; ++it)
        wreg[it] = *(const short8*)&W[(size_t)((it << 6) + (tid >> 2)) * 256 + k0 + 32 + ((tid & 3) << 3)];
    }
    short8 af = *(const short8*)&As[(w << 4) + l15][k0 + (g << 3)];
    #pragma unroll
    for (int nt = 0; nt < 16; ++nt){
      short8 bf = *(const short8*)&Ws[cur][(nt << 4) + l15][g << 3];
      acc[nt] = __builtin_amdgcn_mfma_f32_16x16x32_bf16(af, bf, acc[nt], 0, 0, 0);
    }
    if (s < 7){
      #pragma unroll
      for (int it = 0; it < 4; ++it)
        *(short8*)&Ws[cur ^ 1][(it << 6) + (tid >> 2)][(tid & 3) << 3] = wreg[it];
    }
    __syncthreads();
    cur ^= 1;
  }

  const int row_l = (w << 4) + (g << 2);
  #pragma unroll
  for (int nt = 0; nt < 16; ++nt){
    const int col = (nt << 4) + l15;
    const float bv = bias[col];
    #pragma unroll
    for (int r = 0; r < 4; ++r){
      const int m = m0 + row_l + r;
      float v = acc[nt][r] + bv;
      if (OT == 1){   // kfrag
        const int b_ = m >> 8, kvr = m & 255;
        const int knt = kvr >> 4, kl = kvr & 15;
        const int h = col >> 6, half = (col >> 5) & 1, kg = (col >> 3) & 3, kj = col & 7;
        outB[(((((size_t)(b_ * 4 + h) * 16 + knt) * 2 + half) * 4 + kg) * 16 + kl) * 8 + kj] = f2b(v);
      }
      if (OT == 2){   // vfrag
        const int b_ = m >> 8, kvj = m & 255;
        const int jp = (kvj & ~31) | (((kvj >> 2) & 3) << 3) | (((kvj >> 4) & 1) << 2) | (kvj & 3);
        const int h = col >> 6, dp = col & 63;
        const int kk = jp >> 5, vg = (jp >> 3) & 3, vj = jp & 7;
        const int vn2 = dp >> 4, vl = dp & 15;
        outB[(((((size_t)(b_ * 4 + h) * 8 + kk) * 4 + vn2) * 4 + vg) * 16 + vl) * 8 + vj] = f2b(v);
      }
      if (OT == 4){   // standard afrag
        outB[((((size_t)blockIdx.x * 8 + (col >> 5)) * 4 + w) * 64
              + (((col >> 3) & 3) << 4) + (g << 2) + r) * 8 + (col & 7)] = f2b(v);
      }
    }
  }
}

// ---------------- fused MFMA attention (r12-proven, verbatim) ----------------
__global__ __launch_bounds__(256, 2) void attn_k(
    const short* __restrict__ Qf, const short* __restrict__ Kf,
    const short* __restrict__ Vf, const float* __restrict__ cw,
    short* __restrict__ ctx, float* __restrict__ am_out)
{
  extern __shared__ __align__(16) short smem[];   // 32768 shorts = 64KB
  short* Kl = smem;
  short* Vl = smem + 16384;
  const int b = blockIdx.y;
  const int q0 = blockIdx.x << 6;
  const int tid = threadIdx.x;
  const int w = tid >> 6, lane = tid & 63;
  const int l15 = lane & 15, g = lane >> 4;
  const size_t qw = (size_t)b * 4096 + q0 + (w << 4);
  const size_t qblk = qw >> 4;
  const size_t tileQ = qblk >> 2;
  const int wQ = (int)(qblk & 3);
  const size_t tileC = (size_t)b * 64 + blockIdx.x;

#define STG(dst_, src_) do{ _Pragma("unroll")                                        \
  for (int it_ = 0; it_ < 8; ++it_){ int c_ = (it_ << 8) + tid;                      \
    __builtin_amdgcn_global_load_lds((const AS1 void*)((src_) + (c_ << 3)),          \
                                     (AS3 void*)((dst_) + (c_ << 3)), 16, 0, 0); } }while(0)

  unsigned cwp[16][2];
  f32x4 am[16];
  {
    char* reg = (char*)smem + (w << 13);
    #pragma unroll
    for (int j = 0; j < 16; ++j){
      f32x4 v = *(const f32x4*)&cw[(qw + j) * 256 + (lane << 2)];
      u32x2 d = { pk2(v[0], v[1]), pk2(v[2], v[3]) };
      unsigned off = ((j << 9) + (lane << 3)) ^ ((j & 7) << 4);
      *(u32x2*)(reg + off) = d;
    }
    __syncthreads();
    #pragma unroll
    for (int nt = 0; nt < 16; ++nt){
      unsigned base = ((l15 << 9) + (nt << 5) + (g << 3)) ^ ((l15 & 7) << 4);
      cwp[nt][0] = *(const unsigned*)(reg + base);
      cwp[nt][1] = *(const unsigned*)(reg + base + 4);
      am[nt] = {0.f, 0.f, 0.f, 0.f};
    }
    __syncthreads();
  }

  STG(Kl, Kf + ((size_t)(b * 4) << 14));
  __syncthreads();

  for (int h = 0; h < 4; ++h){
    STG(Vl, Vf + ((size_t)(b * 4 + h) << 14));
    short8 qf0 = *(const short8*)&Qf[(((tileQ * 8 + (h << 1)) * 4 + wQ) * 64 + lane) * 8];
    short8 qf1 = *(const short8*)&Qf[(((tileQ * 8 + (h << 1) + 1) * 4 + wQ) * 64 + lane) * 8];

    f32x4 acc[16];
    #pragma unroll
    for (int nt = 0; nt < 16; ++nt) acc[nt] = {0.f, 0.f, 0.f, 0.f};
    #pragma unroll
    for (int nt = 0; nt < 16; ++nt){
      short8 kf0 = *(const short8*)&Kl[(nt << 10) + (lane << 3)];
      acc[nt] = __builtin_amdgcn_mfma_f32_16x16x32_bf16(kf0, qf0, acc[nt], 0, 0, 0);
      short8 kf1 = *(const short8*)&Kl[(nt << 10) + 512 + (lane << 3)];
      acc[nt] = __builtin_amdgcn_mfma_f32_16x16x32_bf16(kf1, qf1, acc[nt], 0, 0, 0);
    }
    __syncthreads();
    if (h < 3) STG(Kl, Kf + ((size_t)(b * 4 + h + 1) << 14));

    float mx = -3.4e38f;
    #pragma unroll
    for (int nt = 0; nt < 16; ++nt){
      float c0 = __uint_as_float(cwp[nt][0] << 16);
      float c1 = __uint_as_float(cwp[nt][0] & 0xffff0000u);
      float c2 = __uint_as_float(cwp[nt][1] << 16);
      float c3 = __uint_as_float(cwp[nt][1] & 0xffff0000u);
      acc[nt][0] = acc[nt][0] * 0.125f + c0;
      acc[nt][1] = acc[nt][1] * 0.125f + c1;
      acc[nt][2] = acc[nt][2] * 0.125f + c2;
      acc[nt][3] = acc[nt][3] * 0.125f + c3;
      mx = fmaxf(mx, fmaxf(fmaxf(acc[nt][0], acc[nt][1]), fmaxf(acc[nt][2], acc[nt][3])));
    }
    mx = fmaxf(mx, __shfl_xor(mx, 16));
    mx = fmaxf(mx, __shfl_xor(mx, 32));
    float sm = 0.f;
    #pragma unroll
    for (int nt = 0; nt < 16; ++nt){
      #pragma unroll
      for (int r = 0; r < 4; ++r){
        float e = __expf(acc[nt][r] - mx);
        acc[nt][r] = e; sm += e;
      }
    }
    sm += __shfl_xor(sm, 16);
    sm += __shfl_xor(sm, 32);
    float inv = 1.f / sm;
    #pragma unroll
    for (int nt = 0; nt < 16; ++nt){
      #pragma unroll
      for (int r = 0; r < 4; ++r){
        float p = acc[nt][r] * inv;
        acc[nt][r] = p;
        am[nt][r] += 0.25f * p;
      }
    }
    f32x4 oc[4] = {{0,0,0,0},{0,0,0,0},{0,0,0,0},{0,0,0,0}};
    #pragma unroll
    for (int kk = 0; kk < 8; ++kk){
      union { short8 s; unsigned u[4]; } pa;
      pa.u[0] = pk2(acc[2 * kk][0],     acc[2 * kk][1]);
      pa.u[1] = pk2(acc[2 * kk][2],     acc[2 * kk][3]);
      pa.u[2] = pk2(acc[2 * kk + 1][0], acc[2 * kk + 1][1]);
      pa.u[3] = pk2(acc[2 * kk + 1][2], acc[2 * kk + 1][3]);
      #pragma unroll
      for (int n2 = 0; n2 < 4; ++n2){
        short8 vb = *(const short8*)&Vl[(((kk << 2) + n2) << 9) + (lane << 3)];
        oc[n2] = __builtin_amdgcn_mfma_f32_16x16x32_bf16(pa.s, vb, oc[n2], 0, 0, 0);
      }
    }
    #pragma unroll
    for (int n2 = 0; n2 < 4; ++n2){
      const int sctx = (h << 1) + (n2 >> 1);
      const int gctx = ((n2 & 1) << 1) + (l15 >> 3);
      const int j = l15 & 7;
      #pragma unroll
      for (int r = 0; r < 4; ++r)
        ctx[(((tileC * 8 + sctx) * 4 + w) * 64 + (gctx << 4) + (g << 2) + r) * 8 + j]
            = f2b(oc[n2][r]);
    }
    __syncthreads();
  }

  {
    char* reg = (char*)smem + (w << 14);
    #pragma unroll
    for (int nt = 0; nt < 16; ++nt){
      unsigned off = ((l15 << 10) + (nt << 6) + (g << 4)) ^ ((l15 & 7) << 4);
      *(f32x4*)(reg + off) = am[nt];
    }
    __syncthreads();
    #pragma unroll
    for (int i2 = 0; i2 < 16; ++i2){
      unsigned fb = (tid << 4) + (i2 << 12);
      unsigned rowin = (fb >> 10) & 15;
      f32x4 v = *(const f32x4*)((char*)smem + (fb ^ ((rowin & 7) << 4)));
      unsigned row = fb >> 10;
      *(f32x4*)&am_out[((size_t)b * 4096 + q0 + row) * 256 + ((fb & 1023) >> 2)] = v;
    }
  }
#undef STG
}

// ---------------- fused tail: O-proj(+res)+LN -> M1(+GELU) -> M2(+res) ------
// Block = 1 tile (64 rows), 4 waves. LDS 66560B = As(33792, col^g swizzle)
// + Ws dbuf(2x16384, linear, global_load_lds-staged from stage-order Wst).
// k-loops use counted vmcnt(4) + raw barriers (m201/T4 pattern): staged loads
// for slice s+1 stay in flight across the barrier; no full drains in-loop.
// As swizzle: col' = col ^ (((row>>2)&3)<<3) — separates the 4 g-groups of a
// scalar-write instruction into disjoint 16B regions (write conflict-free),
// preserves 16B read contiguity (read boff ^= ((row>>2)&3)<<4).
__global__ __launch_bounds__(256, 2) void tail_k(
    const short* __restrict__ ctxaf, const short* __restrict__ Wst,
    const float* __restrict__ b_o, const float* __restrict__ b_m1,
    const float* __restrict__ b_m2, const float* __restrict__ node,
    const float* __restrict__ lng, const float* __restrict__ lnb,
    float* __restrict__ outF)
{
  extern __shared__ __align__(16) short lds[];
  short* Ws0 = lds + 16896;   // As occupies [0, 16896) shorts (64*264)
  short* Ws1 = Ws0 + 8192;
  const int tid = threadIdx.x;
  const int tile = blockIdx.x;
  const int m0 = tile << 6;
  const int w = tid >> 6, lane = tid & 63;
  const int l15 = lane & 15, g = lane >> 4;
  const int row_l = (w << 4) + (g << 2);

#define ASW(row_, col_) (*(short*)((char*)lds + (row_) * 528 + \
    (((col_) ^ ((((row_) >> 2) & 3) << 3)) << 1)))
#define ASR8(row_, boff_) (*(const short8*)((char*)lds + (row_) * 528 + \
    ((boff_) ^ ((((row_) >> 2) & 3) << 4))))
#define STGW(dst_, wmat_, s_) do{ _Pragma("unroll")                                  \
  for (int it_ = 0; it_ < 4; ++it_){ int c_ = (it_ << 8) + tid;                      \
    __builtin_amdgcn_global_load_lds(                                               \
        (const AS1 void*)((wmat_) + ((size_t)(s_) << 13) + (c_ << 3)),              \
        (AS3 void*)((dst_) + (c_ << 3)), 16, 0, 0); } }while(0)
  // counted-vmcnt k-loop body (T4): stage s+1, wait slice s only, raw barriers
#define KLOOP(WMAT, AF_EXPR)                                                         \
  do{ int cur = 0;                                                                   \
    _Pragma("unroll")                                                                \
    for (int s = 0; s < 8; ++s){                                                     \
      short* rbuf = cur ? Ws1 : Ws0;                                                 \
      short* sbuf = cur ? Ws0 : Ws1;                                                 \
      if (s < 7){ STGW(sbuf, WMAT, s + 1);                                           \
        asm volatile("s_waitcnt vmcnt(4)" ::: "memory");                             \
      } else {                                                                       \
        asm volatile("s_waitcnt vmcnt(0)" ::: "memory");                             \
      }                                                                              \
      __builtin_amdgcn_s_barrier();                                                  \
      const short8 af = (AF_EXPR);                                                   \
      _Pragma("unroll")                                                              \
      for (int nt = 0; nt < 16; ++nt){                                               \
        short8 bf = *(const short8*)&rbuf[((nt << 4) + l15) * 32 + (g << 3)];        \
        acc[nt] = __builtin_amdgcn_mfma_f32_16x16x32_bf16(af, bf, acc[nt], 0, 0, 0); \
      }                                                                              \
      __builtin_amdgcn_s_barrier();                                                  \
      cur ^= 1;                                                                      \
    } }while(0)

  f32x4 acc[16];

  // ================= phase O: A = ctx afrag (hoisted regs) =================
  STGW(Ws0, Wst, 0);
  short8 afr[8];
  #pragma unroll
  for (int s = 0; s < 8; ++s)
    afr[s] = *(const short8*)&ctxaf[((((size_t)tile << 3) + s) * 4 + w) * 512 + (lane << 3)];
  #pragma unroll
  for (int nt = 0; nt < 16; ++nt) acc[nt] = {0.f, 0.f, 0.f, 0.f};
  KLOOP(Wst, afr[s]);

  // x = acc + b_o + node, packed bf16 (32 regs); LN(x) -> As (swizzled)
  unsigned xvp[16][2];
  #pragma unroll
  for (int nt = 0; nt < 16; ++nt){
    const int col = (nt << 4) + l15;
    const float bv = b_o[col];
    float x0 = acc[nt][0] + bv + node[(size_t)(m0 + row_l + 0) * 256 + col];
    float x1 = acc[nt][1] + bv + node[(size_t)(m0 + row_l + 1) * 256 + col];
    float x2 = acc[nt][2] + bv + node[(size_t)(m0 + row_l + 2) * 256 + col];
    float x3 = acc[nt][3] + bv + node[(size_t)(m0 + row_l + 3) * 256 + col];
    xvp[nt][0] = pk2(x0, x1);
    xvp[nt][1] = pk2(x2, x3);
  }
  #pragma unroll
  for (int r = 0; r < 4; ++r){
    float s1 = 0.f, s2 = 0.f;
    #pragma unroll
    for (int nt = 0; nt < 16; ++nt){
      float v = (r == 0) ? ulo(xvp[nt][0]) : (r == 1) ? uhi(xvp[nt][0])
              : (r == 2) ? ulo(xvp[nt][1]) : uhi(xvp[nt][1]);
      s1 += v; s2 += v * v;
    }
    #pragma unroll
    for (int off = 1; off < 16; off <<= 1){ s1 += __shfl_xor(s1, off); s2 += __shfl_xor(s2, off); }
    const float mu = s1 * 0.00390625f;
    const float rs = rsqrtf(s2 * 0.00390625f - mu * mu + 1e-5f);
    #pragma unroll
    for (int nt = 0; nt < 16; ++nt){
      const int col = (nt << 4) + l15;
      float v = (r == 0) ? ulo(xvp[nt][0]) : (r == 1) ? uhi(xvp[nt][0])
              : (r == 2) ? ulo(xvp[nt][1]) : uhi(xvp[nt][1]);
      ASW(row_l + r, col) = f2b((v - mu) * rs * lng[col] + lnb[col]);
    }
  }

  // ================= phase M1 (af per-step from As) =================
  {
    const short* Wm1 = Wst + 65536;
    STGW(Ws0, Wm1, 0);
    __syncthreads();                     // As writes + slice0 visible, vmcnt reset
    #pragma unroll
    for (int nt = 0; nt < 16; ++nt) acc[nt] = {0.f, 0.f, 0.f, 0.f};
    KLOOP(Wm1, ASR8((w << 4) + l15, (s << 6) + (g << 4)));
  }
  // GELU(acc + b_m1) -> As (swizzled)
  #pragma unroll
  for (int nt = 0; nt < 16; ++nt){
    const int col = (nt << 4) + l15;
    const float bv = b_m1[col];
    #pragma unroll
    for (int r = 0; r < 4; ++r){
      float v = acc[nt][r] + bv;
      v = 0.5f * v * (1.0f + erff(v * 0.70710678118f));
      ASW(row_l + r, col) = f2b(v);
    }
  }

  // ================= phase M2 =================
  {
    const short* Wm2 = Wst + 131072;
    STGW(Ws0, Wm2, 0);
    __syncthreads();
    #pragma unroll
    for (int nt = 0; nt < 16; ++nt) acc[nt] = {0.f, 0.f, 0.f, 0.f};
    KLOOP(Wm2, ASR8((w << 4) + l15, (s << 6) + (g << 4)));
  }
  // out = acc + b_m2 + x
  #pragma unroll
  for (int nt = 0; nt < 16; ++nt){
    const int col = (nt << 4) + l15;
    const float bv = b_m2[col];
    #pragma unroll
    for (int r = 0; r < 4; ++r){
      float xr = (r == 0) ? ulo(xvp[nt][0]) : (r == 1) ? uhi(xvp[nt][0])
               : (r == 2) ? ulo(xvp[nt][1]) : uhi(xvp[nt][1]);
      outF[(size_t)(m0 + row_l + r) * 256 + col] = acc[nt][r] + bv + xr;
    }
  }
#undef ASW
#undef ASR8
#undef STGW
#undef KLOOP
}

extern "C" void kernel_launch(void* const* d_in, const int* in_sizes, int n_in,
                              void* d_out, int out_size, void* d_ws, size_t ws_size,
                              hipStream_t stream)
{
  const float* node_emb = (const float*)d_in[0];
  const float* cluster  = (const float*)d_in[1];
  const float* cw       = (const float*)d_in[2];
  const float* ln_q_g   = (const float*)d_in[3];
  const float* ln_q_b   = (const float*)d_in[4];
  const float* ln_kv_g  = (const float*)d_in[5];
  const float* ln_kv_b  = (const float*)d_in[6];
  const float* ln_o_g   = (const float*)d_in[7];
  const float* ln_o_b   = (const float*)d_in[8];
  const float* W_q  = (const float*)d_in[9];  const float* b_q  = (const float*)d_in[10];
  const float* W_k  = (const float*)d_in[11]; const float* b_k  = (const float*)d_in[12];
  const float* W_v  = (const float*)d_in[13]; const float* b_v  = (const float*)d_in[14];
  const float* W_o  = (const float*)d_in[15]; const float* b_o  = (const float*)d_in[16];
  const float* W_m1 = (const float*)d_in[17]; const float* b_m1 = (const float*)d_in[18];
  const float* W_m2 = (const float*)d_in[19]; const float* b_m2 = (const float*)d_in[20];

  char* ws = (char*)d_ws;
  short* Wbf   = (short*)ws;                                   // 786,432 B row-major (6 mats)
  short* Wst   = (short*)(ws + 786432);                        // 393,216 B stage-order (O,M1,M2)
  short* bufA  = (short*)(ws + 1179648);                       // 16.78 MB: ctx afrag
  short* bufB  = (short*)(ws + 1179648 + 16777216);            // 16.78 MB: Q afrag
  short* kvin  = (short*)(ws + 1179648 + 2 * 16777216);        // 1 MB
  short* kfrag = (short*)(ws + 1179648 + 2 * 16777216 + 1048576);
  short* vfrag = (short*)(ws + 1179648 + 2 * 16777216 + 2 * 1048576);

  float* outF = (float*)d_out;            // final out (written only by tail_k)
  float* amof = (float*)d_out + 8388608;  // attn_matrix

  hipFuncSetAttribute((const void*)attn_k, hipFuncAttributeMaxDynamicSharedMemorySize, 65536);
  hipFuncSetAttribute((const void*)tail_k, hipFuncAttributeMaxDynamicSharedMemorySize, 66560);

  cvt_w<<<1536, 256, 0, stream>>>(W_q, W_k, W_v, W_o, W_m1, W_m2, Wbf, Wst);
  ln_k<<<2048, 256, 0, stream>>>(cluster, ln_kv_g, ln_kv_b, kvin);
  // Q projection: fused input-LN, afrag output -> bufB
  gemmW<4,1><<<512, 256, 0, stream>>>(nullptr, node_emb, Wbf, b_q, bufB, ln_q_g, ln_q_b);
  // K / V projections -> kfrag / vfrag
  gemmW<1,0><<<32, 256, 0, stream>>>(kvin, nullptr, Wbf + 65536,  b_k, kfrag, nullptr, nullptr);
  gemmW<2,0><<<32, 256, 0, stream>>>(kvin, nullptr, Wbf + 131072, b_v, vfrag, nullptr, nullptr);
  // attention (ctx afrag -> bufA, attn_matrix -> d_out 2nd half)
  attn_k<<<dim3(64, 8), 256, 65536, stream>>>(bufB, kfrag, vfrag, cw, bufA, amof);
  // fused tail: O(+res)+LN -> M1(+GELU) -> M2(+res) -> out
  tail_k<<<512, 256, 66560, stream>>>(bufA, Wst, b_o, b_m1, b_m2,
      node_emb, ln_o_g, ln_o_b, outF);
}